// Round 8
// baseline (1059.864 us; speedup 1.0000x reference)
//
#include <hip/hip_runtime.h>
#include <hip/hip_bf16.h>

#define B_ 4
#define N_ 4096
#define NS_ 1024
#define KNN_ 32
#define NPOS_ 131072   /* B_*NS_*KNN_ */
#define BN_EPS_ 1e-5f

using bf16 = __hip_bfloat16;
typedef unsigned short us;
typedef __attribute__((ext_vector_type(8))) short short8;
typedef __attribute__((ext_vector_type(4))) float f32x4;
typedef unsigned long long ull;

__device__ __forceinline__ float bf2f(bf16 h){ return __bfloat162float(h); }
__device__ __forceinline__ us f2bfbits(float x){
    bf16 h = __float2bfloat16(x);
    return *reinterpret_cast<us*>(&h);
}
__device__ __forceinline__ float bits2f(us u){
    unsigned v = ((unsigned)u)<<16; return __uint_as_float(v);
}
__device__ __forceinline__ void unpack8(uint4 v, float* f){
    f[0]=__uint_as_float((v.x&0xFFFFu)<<16); f[1]=__uint_as_float(v.x&0xFFFF0000u);
    f[2]=__uint_as_float((v.y&0xFFFFu)<<16); f[3]=__uint_as_float(v.y&0xFFFF0000u);
    f[4]=__uint_as_float((v.z&0xFFFFu)<<16); f[5]=__uint_as_float(v.z&0xFFFF0000u);
    f[6]=__uint_as_float((v.w&0xFFFFu)<<16); f[7]=__uint_as_float(v.w&0xFFFF0000u);
}
__device__ __forceinline__ uint4 pack8(const float* f){
    uint4 v;
    v.x = (unsigned)f2bfbits(f[0]) | ((unsigned)f2bfbits(f[1])<<16);
    v.y = (unsigned)f2bfbits(f[2]) | ((unsigned)f2bfbits(f[3])<<16);
    v.z = (unsigned)f2bfbits(f[4]) | ((unsigned)f2bfbits(f[5])<<16);
    v.w = (unsigned)f2bfbits(f[6]) | ((unsigned)f2bfbits(f[7])<<16);
    return v;
}
__device__ __forceinline__ unsigned fmono(float v){
    unsigned u = __float_as_uint(v);
    return (u & 0x80000000u) ? ~u : (u | 0x80000000u);
}

// ---- DPP wave64 reductions ----
template<int CTRL, int ROWM>
__device__ __forceinline__ float dppmaxf(float x){
    int xi = __float_as_int(x);
    int yi = __builtin_amdgcn_update_dpp(xi, xi, CTRL, ROWM, 0xF, false);
    return fmaxf(x, __int_as_float(yi));
}
template<int CTRL, int ROWM>
__device__ __forceinline__ float dppminf(float x){
    int xi = __float_as_int(x);
    int yi = __builtin_amdgcn_update_dpp(xi, xi, CTRL, ROWM, 0xF, false);
    return fminf(x, __int_as_float(yi));
}
__device__ __forceinline__ float wave_max_f32(float x){
    x = dppmaxf<0x111,0xF>(x);
    x = dppmaxf<0x112,0xF>(x);
    x = dppmaxf<0x114,0xF>(x);
    x = dppmaxf<0x118,0xF>(x);
    x = dppmaxf<0x142,0xA>(x);
    x = dppmaxf<0x143,0xC>(x);
    return __int_as_float(__builtin_amdgcn_readlane(__float_as_int(x), 63));
}
__device__ __forceinline__ float wave_min_f32(float x){
    x = dppminf<0x111,0xF>(x);
    x = dppminf<0x112,0xF>(x);
    x = dppminf<0x114,0xF>(x);
    x = dppminf<0x118,0xF>(x);
    x = dppminf<0x142,0xA>(x);
    x = dppminf<0x143,0xC>(x);
    return __int_as_float(__builtin_amdgcn_readlane(__float_as_int(x), 63));
}
// sum across each 16-lane DPP row; lane (lane&15)==15 holds row total
__device__ __forceinline__ float rowsum16(float x){
    x += __int_as_float(__builtin_amdgcn_update_dpp(0, __float_as_int(x), 0x111, 0xF, 0xF, true));
    x += __int_as_float(__builtin_amdgcn_update_dpp(0, __float_as_int(x), 0x112, 0xF, 0xF, true));
    x += __int_as_float(__builtin_amdgcn_update_dpp(0, __float_as_int(x), 0x114, 0xF, 0xF, true));
    x += __int_as_float(__builtin_amdgcn_update_dpp(0, __float_as_int(x), 0x118, 0xF, 0xF, true));
    return x;
}
// max/min across each 16-lane DPP row; lane (lane&15)==15 holds row result
__device__ __forceinline__ float rowmax16(float x){
    x = dppmaxf<0x111,0xF>(x);
    x = dppmaxf<0x112,0xF>(x);
    x = dppmaxf<0x114,0xF>(x);
    x = dppmaxf<0x118,0xF>(x);
    return x;
}
__device__ __forceinline__ float rowmin16(float x){
    x = dppminf<0x111,0xF>(x);
    x = dppminf<0x112,0xF>(x);
    x = dppminf<0x114,0xF>(x);
    x = dppminf<0x118,0xF>(x);
    return x;
}
// full 64-lane sum -> broadcast via readlane 63
__device__ __forceinline__ float wave_sum_f32(float x){
    x = rowsum16(x);
    x += __int_as_float(__builtin_amdgcn_update_dpp(0, __float_as_int(x), 0x142, 0xA, 0xF, false));
    x += __int_as_float(__builtin_amdgcn_update_dpp(0, __float_as_int(x), 0x143, 0xC, 0xF, false));
    return __int_as_float(__builtin_amdgcn_readlane(__float_as_int(x), 63));
}
__device__ __forceinline__ float max16(const float* v){
    float a = fmaxf(fmaxf(fmaxf(v[0],v[1]),v[2]),v[3]);
    float b = fmaxf(fmaxf(fmaxf(v[4],v[5]),v[6]),v[7]);
    float c = fmaxf(fmaxf(fmaxf(v[8],v[9]),v[10]),v[11]);
    float d = fmaxf(fmaxf(fmaxf(v[12],v[13]),v[14]),v[15]);
    return fmaxf(fmaxf(a,b), fmaxf(c,d));
}
__device__ __forceinline__ float min16(const float* v){
    float a = fminf(fminf(fminf(v[0],v[1]),v[2]),v[3]);
    float b = fminf(fminf(fminf(v[4],v[5]),v[6]),v[7]);
    float c = fminf(fminf(fminf(v[8],v[9]),v[10]),v[11]);
    float d = fminf(fminf(fminf(v[12],v[13]),v[14]),v[15]);
    return fminf(fminf(a,b), fminf(c,d));
}

// Partial-stats layout: part[(ch*2+k)*64 + slot], ch in [0,1024)
#define NSLOT 64

// -------------------- BN coef from 64-slot partials (bn3) --------------------
__global__ __launch_bounds__(256) void bn_coef(const float* __restrict__ part,
                                               const float* __restrict__ g,
                                               const float* __restrict__ be,
                                               int chbase, int C,
                                               float2* __restrict__ ab){
    int c = blockIdx.x*256 + threadIdx.x;
    if (c < C){
        const float* ps = part + (size_t)(chbase+c)*2*NSLOT;
        float s = 0.f, q = 0.f;
        #pragma unroll 8
        for (int i=0;i<NSLOT;i++){ s += ps[i]; q += ps[NSLOT+i]; }
        const float inv = 1.0f/(float)NPOS_;
        float mean = s*inv;
        float var  = q*inv - mean*mean;
        float a = g[c]*rsqrtf(var + BN_EPS_);
        ab[c] = make_float2(a, be[c] - mean*a);
    }
}

// -------------------- mega: FPS producer + preps + convknn consumers ----------
// FPS body is the R0-proven form (fastest measured: 662-672 us). R1-R4
// established empirically that setprio / CU-exclusivity / relaxed barriers /
// deferred writes / dual-batch ILP ALL regress it -- do not touch this loop.
__global__ __launch_bounds__(256) void mega_kernel(const float* __restrict__ p,
                                                   const float* __restrict__ f,
                                                   float* __restrict__ cntrd,
                                                   float* __restrict__ part,
                                                   int* __restrict__ prog,
                                                   int* __restrict__ w26flag,
                                                   const float* __restrict__ w1,
                                                   const float* __restrict__ w2,
                                                   float* __restrict__ W26,
                                                   const float* __restrict__ b2,
                                                   const float* __restrict__ w3,
                                                   us* __restrict__ whi3,
                                                   const float* __restrict__ w4,
                                                   us* __restrict__ whi4,
                                                   bf16* __restrict__ z2,
                                                   unsigned* __restrict__ mxmn2){
    __shared__ float4 pxyz[N_];
    __shared__ ull warr[2][4];
    __shared__ int knnS[32];
    __shared__ float Ws[6][256];
    __shared__ float xs[6][32];
    __shared__ int ciS;
    const int bid = blockIdx.x;
    const int t = threadIdx.x;
    const int lane = t & 63;
    const int wave = t >> 6;

    if (bid < 4){
        // ---------------- FPS producer (proven R0 body -- do not modify) -----
        const int b = bid;
        const float* pb = p + (size_t)b*N_*3;
        float rx[16], ry[16], rz[16], dist[16];
        #pragma unroll
        for (int j=0;j<16;j++){
            int i = t*16+j;
            float x = pb[i*3+0];
            float y = pb[i*3+1];
            float z = pb[i*3+2];
            rx[j]=x; ry[j]=y; rz[j]=z;
            pxyz[i] = make_float4(x,y,z,0.f);
            dist[j]=1e10f;
        }
        __syncthreads();
        float4 c = pxyz[0];
        if (t==0){
            atomicExch(&prog[b*NS_], 1);
            cntrd[(size_t)(b*NS_)*3+0] = c.x;
            cntrd[(size_t)(b*NS_)*3+1] = c.y;
            cntrd[(size_t)(b*NS_)*3+2] = c.z;
        }
        for (int s=1; s<NS_; s++){
            #pragma unroll
            for (int j=0;j<16;j++){
                float dx = __fsub_rn(rx[j],c.x);
                float dy = __fsub_rn(ry[j],c.y);
                float dz = __fsub_rn(rz[j],c.z);
                float d  = __fadd_rn(__fadd_rn(__fmul_rn(dx,dx),__fmul_rn(dy,dy)),__fmul_rn(dz,dz));
                dist[j] = fminf(dist[j], d);
            }
            float lmax = max16(dist);
            float wmax = wave_max_f32(lmax);
            unsigned msk = 0;
            #pragma unroll
            for (int j=0;j<16;j++) msk |= (dist[j]==wmax) ? (1u<<j) : 0u;
            ull ball = __ballot(msk != 0);
            int srclane = (int)__builtin_ctzll(ball);
            unsigned lmsk = (unsigned)__builtin_amdgcn_readlane((int)msk, srclane);
            int widx = (wave*64 + srclane)*16 + (int)__builtin_ctz(lmsk);
            if (lane==0)
                warr[s&1][wave] = ((ull)__float_as_uint(wmax)<<32) | (0xFFFFFFFFu - (unsigned)widx);
            __syncthreads();
            ull g0 = warr[s&1][0], g1 = warr[s&1][1], g2 = warr[s&1][2], g3 = warr[s&1][3];
            ull ga = g0 > g1 ? g0 : g1;
            ull gb = g2 > g3 ? g2 : g3;
            ull g  = ga > gb ? ga : gb;
            int cur = (int)(0xFFFFFFFFu - (unsigned)(g & 0xFFFFFFFFull));
            c = pxyz[cur];
            if (t==0){
                atomicExch(&prog[b*NS_+s], cur+1);
                cntrd[(size_t)(b*NS_+s)*3+0] = c.x;
                cntrd[(size_t)(b*NS_+s)*3+1] = c.y;
                cntrd[(size_t)(b*NS_+s)*3+2] = c.z;
            }
        }
        return;
    }
    if (bid == 4){
        float acc[6] = {0,0,0,0,0,0};
        for (int k=0;k<256;k++){
            float w2v = w2[t*256+k];
            #pragma unroll
            for (int j=0;j<6;j++) acc[j] = fmaf(w2v, w1[k*6+j], acc[j]);
        }
        #pragma unroll
        for (int j=0;j<6;j++) W26[j*256+t] = acc[j];
        __syncthreads();
        if (t==0){ __threadfence(); atomicExch(w26flag, 1); }
        return;
    }
    if (bid < 1029){              // cast w3 -> bf16
        int i = (bid-5)*256 + t;
        whi3[i] = f2bfbits(w3[i]);
        return;
    }
    if (bid < 1541){              // cast w4 -> bf16
        int i = (bid-1029)*256 + t;
        whi4[i] = f2bfbits(w4[i]);
        return;
    }
    // ---------------- convknn worker ----------------
    const int wid = bid - 1541;
    const int b = wid & 3;
    const int si = wid >> 2;
    const int sidx = b*NS_ + si;
    const float* pb = p + (size_t)b*N_*3;
    if (t == 0){
        int v;
        while ((v = atomicAdd(&prog[sidx], 0)) == 0) { __builtin_amdgcn_s_sleep(8); }
        ciS = v - 1;
    }
    __syncthreads();
    const int ci = ciS;
    float cx = pb[ci*3+0];
    float cy = pb[ci*3+1];
    float cz = pb[ci*3+2];
    float c2 = __fadd_rn(__fadd_rn(__fmul_rn(cx,cx),__fmul_rn(cy,cy)),__fmul_rn(cz,cz));
    float d2[16];
    #pragma unroll
    for (int j=0;j<16;j++){
        int i = t*16+j;
        float x = pb[i*3+0];
        float y = pb[i*3+1];
        float z = pb[i*3+2];
        float p2 = __fadd_rn(__fadd_rn(__fmul_rn(x,x),__fmul_rn(y,y)),__fmul_rn(z,z));
        float dot= __fadd_rn(__fadd_rn(__fmul_rn(cx,x),__fmul_rn(cy,y)),__fmul_rn(cz,z));
        d2[j] = __fsub_rn(__fadd_rn(c2,p2), __fmul_rn(2.0f,dot));
    }
    for (int it=0; it<KNN_; it++){
        float lmin = min16(d2);
        float wmin = wave_min_f32(lmin);
        unsigned msk = 0;
        #pragma unroll
        for (int j=0;j<16;j++) msk |= (d2[j]==wmin) ? (1u<<j) : 0u;
        ull ball = __ballot(msk != 0);
        int srclane = (int)__builtin_ctzll(ball);
        unsigned lmsk = (unsigned)__builtin_amdgcn_readlane((int)msk, srclane);
        int widx = (wave*64 + srclane)*16 + (int)__builtin_ctz(lmsk);
        if (lane==0)
            warr[it&1][wave] = ((ull)fmono(wmin)<<32) | (unsigned)widx;
        __syncthreads();
        ull g0 = warr[it&1][0], g1 = warr[it&1][1], g2 = warr[it&1][2], g3 = warr[it&1][3];
        ull ga = g0 < g1 ? g0 : g1;
        ull gb = g2 < g3 ? g2 : g3;
        ull g  = ga < gb ? ga : gb;
        int idx = (int)(g & 0xFFFFFFFFull);
        if ((idx>>4)==t) d2[idx & 15] = INFINITY;
        if (t==0) knnS[it] = idx;
    }
    if (t == 0){ while (atomicAdd(w26flag, 0) == 0) { __builtin_amdgcn_s_sleep(8); } __threadfence(); }
    __syncthreads();
    #pragma unroll
    for (int r=0;r<6;r++) Ws[r][t] = W26[r*256+t];
    if (t < 32){
        int i = knnS[t];
        const float* fb = f + (size_t)b*3*N_;
        xs[0][t] = pb[i*3+0];
        xs[1][t] = pb[i*3+1];
        xs[2][t] = pb[i*3+2];
        xs[3][t] = fb[0*N_+i];
        xs[4][t] = fb[1*N_+i];
        xs[5][t] = fb[2*N_+i];
    }
    __syncthreads();
    float w0=Ws[0][t], w1v=Ws[1][t], w2v=Ws[2][t], w3v=Ws[3][t], w4v=Ws[4][t], w5v=Ws[5][t];
    float bias = b2[t];
    bf16* zrow = z2 + (size_t)t*NPOS_ + (size_t)sidx*KNN_;
    float ssum = 0.f, sq = 0.f;
    float mxv = -3.4e38f, mnv = 3.4e38f;   // per-(c,sidx) extrema of bf16(z2)
    for (int k0=0;k0<32;k0+=8){
        float y[8];
        #pragma unroll
        for (int u=0;u<8;u++){
            int k = k0+u;
            float acc = bias;
            acc = fmaf(w0, xs[0][k], acc);
            acc = fmaf(w1v,xs[1][k], acc);
            acc = fmaf(w2v,xs[2][k], acc);
            acc = fmaf(w3v,xs[3][k], acc);
            acc = fmaf(w4v,xs[4][k], acc);
            acc = fmaf(w5v,xs[5][k], acc);
            float vr = bits2f(f2bfbits(acc));
            ssum += vr; sq = fmaf(vr, vr, sq);
            mxv = fmaxf(mxv, vr); mnv = fminf(mnv, vr);
            y[u] = acc;
        }
        *reinterpret_cast<uint4*>(zrow + k0) = pack8(y);
    }
    // packed extrema, [sidx][c] layout: each worker writes its own 1KB run
    mxmn2[(size_t)sidx*256 + t] = (unsigned)f2bfbits(mxv) | ((unsigned)f2bfbits(mnv)<<16);
    const int slot = wid & (NSLOT-1);
    atomicAdd(&part[(size_t)(t*2+0)*NSLOT + slot], ssum);
    atomicAdd(&part[(size_t)(t*2+1)*NSLOT + slot], sq);
}

// -------- xm = max over K of relu(a*x+b) via packed per-(bs,c) extrema --------
// Fused bn2-coef: thread t derives channel t's (a,b) from part with the exact
// bn_coef op sequence (bit-identical); block 0 publishes ab2 for gemm5.
__global__ __launch_bounds__(256) void xm_kernel(const unsigned* __restrict__ mxmn2,
                                                 const float* __restrict__ part,
                                                 const float* __restrict__ g2,
                                                 const float* __restrict__ be2,
                                                 float2* __restrict__ ab2out,
                                                 bf16* __restrict__ xm){
    const int t = threadIdx.x;
    const int bs0 = blockIdx.x * 32;
    // bn2 coefficients for channel t (replicates bn_coef exactly)
    const float* ps = part + (size_t)t*2*NSLOT;
    float sacc = 0.f, qacc = 0.f;
    #pragma unroll 8
    for (int i=0;i<NSLOT;i++){ sacc += ps[i]; qacc += ps[NSLOT+i]; }
    const float inv = 1.0f/(float)NPOS_;
    float mean = sacc*inv;
    float var  = qacc*inv - mean*mean;
    float a = g2[t]*rsqrtf(var + BN_EPS_);
    float bc = be2[t] - mean*a;
    if (blockIdx.x == 0) ab2out[t] = make_float2(a, bc);
    us y[32];
    #pragma unroll
    for (int i=0;i<32;i++){
        unsigned v = mxmn2[(size_t)(bs0+i)*256 + t];
        float x = (a >= 0.f) ? bits2f((us)(v & 0xFFFFu)) : bits2f((us)(v >> 16));
        y[i] = f2bfbits(fmaxf(fmaf(x, a, bc), 0.0f));
    }
    uint4* dst = reinterpret_cast<uint4*>(reinterpret_cast<us*>(xm) + (size_t)t*4096 + bs0);
    const uint4* src = reinterpret_cast<const uint4*>(y);
    dst[0]=src[0]; dst[1]=src[1]; dst[2]=src[2]; dst[3]=src[3];
}

// -------------------- small fp32 GEMM (t3 only), 64x128 tiles -----------------
// 256 blocks (full machine; was 128 = half idle on a VALU-bound fp32 GEMM).
__global__ __launch_bounds__(256) void gemm128(const float* __restrict__ A, int lda, int aoff,
                                               const bf16* __restrict__ B,
                                               int M, int N, int K,
                                               float* __restrict__ Cf){
    __shared__ float As[16][64];
    __shared__ float Bs[16][128];
    const int tid = threadIdx.x;
    const int tx = tid & 15, ty = tid >> 4;
    const int m0 = blockIdx.y*64, n0 = blockIdx.x*128;
    float acc[4][8];
    #pragma unroll
    for (int i=0;i<4;i++)
        #pragma unroll
        for (int j=0;j<8;j++) acc[i][j]=0.f;
    const int arow = tid >> 2, akg = tid & 3;
    const int bkk = tid >> 4, bng = tid & 15;
    for (int k0=0;k0<K;k0+=16){
        const float* aptr = A + (size_t)(m0+arow)*lda + aoff + k0 + akg*4;
        float4 a0 = *reinterpret_cast<const float4*>(aptr);
        As[akg*4+0][arow]=a0.x; As[akg*4+1][arow]=a0.y;
        As[akg*4+2][arow]=a0.z; As[akg*4+3][arow]=a0.w;
        uint4 bv = *reinterpret_cast<const uint4*>(B + (size_t)(k0+bkk)*N + n0 + bng*8);
        float bf[8]; unpack8(bv, bf);
        *reinterpret_cast<float4*>(&Bs[bkk][bng*8+0]) = make_float4(bf[0],bf[1],bf[2],bf[3]);
        *reinterpret_cast<float4*>(&Bs[bkk][bng*8+4]) = make_float4(bf[4],bf[5],bf[6],bf[7]);
        __syncthreads();
        #pragma unroll
        for (int kk=0;kk<16;kk++){
            float a[4], b[8];
            *reinterpret_cast<float4*>(&a[0]) = *reinterpret_cast<float4*>(&As[kk][ty*4]);
            *reinterpret_cast<float4*>(&b[0]) = *reinterpret_cast<float4*>(&Bs[kk][tx*8+0]);
            *reinterpret_cast<float4*>(&b[4]) = *reinterpret_cast<float4*>(&Bs[kk][tx*8+4]);
            #pragma unroll
            for (int i=0;i<4;i++)
                #pragma unroll
                for (int j=0;j<8;j++)
                    acc[i][j] = fmaf(a[i], b[j], acc[i][j]);
        }
        __syncthreads();
    }
    const int n = n0 + tx*8;
    #pragma unroll
    for (int i=0;i<4;i++){
        int m = m0 + ty*4 + i;
        *reinterpret_cast<float4*>(Cf + (size_t)m*N + n + 0) = make_float4(acc[i][0],acc[i][1],acc[i][2],acc[i][3]);
        *reinterpret_cast<float4*>(Cf + (size_t)m*N + n + 4) = make_float4(acc[i][4],acc[i][5],acc[i][6],acc[i][7]);
    }
}

// -------------------- MFMA GEMM: LDS-staged bf16 A, fused-BN B, fused stats ---
// When mxmnout!=nullptr: do NOT write the dense output; instead emit packed
// per-(row,sidx) max/min over the 32 k-columns (pool fusion for final maxpool).
// B-staging: 2 x uint4 vector loads per thread (was 16 scalar us loads),
// repacked to the same Bs[n][k] layout via 8 ds_write_b32. Values bit-identical.
#define LDK 40
__global__ __launch_bounds__(256) void gemm_mfma(const us* __restrict__ Whi,
                                                 int ldw, int aoff,
                                                 const bf16* __restrict__ act, int K,
                                                 const float2* __restrict__ ab,
                                                 bf16* __restrict__ out,
                                                 const float* __restrict__ t3,
                                                 float* __restrict__ part, int chbase,
                                                 unsigned* __restrict__ mxmnout){
    __shared__ __align__(16) us AsH[128*LDK];
    __shared__ __align__(16) us Bs [128*LDK];
    __shared__ float t3s[128][4];
    const us* actu = reinterpret_cast<const us*>(act);
    const int t = threadIdx.x;
    // ---- XCD-aware tile assignment (bijective remap of the linear id) ----
    const int nx  = gridDim.x;
    const int nwg = nx * gridDim.y;
    const int hid = blockIdx.y * nx + blockIdx.x;
    const int q8  = nwg >> 3;
    const int logical = (hid & 7) * q8 + (hid >> 3);
    const int mi = logical % nx;
    const int ni = logical / nx;
    const int m0 = mi*128, n0 = ni*128;
    const int wave = t>>6, lane = t&63;
    const int wm = wave>>1, wn = wave&1;
    const int q = lane>>4, col = lane&15;

    if (t3 && t < 128){
        const float* src = t3 + (size_t)(m0+t)*4096 + (n0>>5);
        t3s[t][0]=src[0]; t3s[t][1]=src[1]; t3s[t][2]=src[2]; t3s[t][3]=src[3];
    }

    f32x4 acc[4][4];
    #pragma unroll
    for (int i=0;i<4;i++)
        #pragma unroll
        for (int j=0;j<4;j++) acc[i][j] = (f32x4){0.f,0.f,0.f,0.f};

    const int ar = t>>1, ah = t&1;
    const int bnb = (t & 15) * 8;      // 8 consecutive n per thread
    const int bkb = (t >> 4) * 2;      // 2 consecutive k per thread

    for (int k0=0;k0<K;k0+=32){
        const us* sh = Whi + (size_t)(m0+ar)*ldw + aoff + k0 + ah*16;
        uint4 h0 = *reinterpret_cast<const uint4*>(sh);
        uint4 h1 = *reinterpret_cast<const uint4*>(sh+8);
        *reinterpret_cast<uint4*>(&AsH[ar*LDK + ah*16 + 0]) = h0;
        *reinterpret_cast<uint4*>(&AsH[ar*LDK + ah*16 + 8]) = h1;
        // B: two k-rows x 8 n each, vector loads + per-element BN/ReLU/pack
        {
            const int kA = k0 + bkb, kB = kA + 1;
            uint4 v0 = *reinterpret_cast<const uint4*>(&actu[(size_t)kA*NPOS_ + n0 + bnb]);
            uint4 v1 = *reinterpret_cast<const uint4*>(&actu[(size_t)kB*NPOS_ + n0 + bnb]);
            float fa[8], fb[8];
            unpack8(v0, fa);
            unpack8(v1, fb);
            float2 sA = ab[kA], sB = ab[kB];
            #pragma unroll
            for (int i=0;i<8;i++){
                us ea = f2bfbits(fmaxf(fmaf(fa[i], sA.x, sA.y), 0.0f));
                us eb = f2bfbits(fmaxf(fmaf(fb[i], sB.x, sB.y), 0.0f));
                *reinterpret_cast<unsigned*>(&Bs[(bnb+i)*LDK + bkb]) =
                    (unsigned)ea | ((unsigned)eb << 16);
            }
        }
        __syncthreads();
        short8 bf[4], afh[4];
        #pragma unroll
        for (int tn=0;tn<4;tn++)
            bf[tn] = *reinterpret_cast<const short8*>(&Bs[(wn*64+tn*16+col)*LDK + q*8]);
        #pragma unroll
        for (int tm=0;tm<4;tm++)
            afh[tm] = *reinterpret_cast<const short8*>(&AsH[(wm*64+tm*16+col)*LDK + q*8]);
        #pragma unroll
        for (int tm=0;tm<4;tm++)
            #pragma unroll
            for (int tn=0;tn<4;tn++)
                acc[tm][tn] = __builtin_amdgcn_mfma_f32_16x16x32_bf16(afh[tm], bf[tn], acc[tm][tn], 0, 0, 0);
        __syncthreads();
    }
    const int slot = ni & (NSLOT-1);
    #pragma unroll
    for (int tm=0;tm<4;tm++){
        #pragma unroll
        for (int r=0;r<4;r++){
            int m_l = wm*64 + tm*16 + q*4 + r;
            float srow = 0.f, qrow = 0.f;
            float vr4[4];
            #pragma unroll
            for (int tn=0;tn<4;tn++){
                int n_l = wn*64 + tn*16 + col;
                float vv = acc[tm][tn][r];
                if (t3) vv += t3s[m_l][n_l>>5];
                us hb = f2bfbits(vv);
                if (!mxmnout)
                    reinterpret_cast<us*>(out)[(size_t)(m0+m_l)*NPOS_ + n0 + n_l] = hb;
                float vr = bits2f(hb);
                vr4[tn] = vr;
                srow += vr; qrow = fmaf(vr, vr, qrow);
            }
            srow = rowsum16(srow);
            qrow = rowsum16(qrow);
            if (col == 15){
                atomicAdd(&part[(size_t)((chbase + m0 + m_l)*2+0)*NSLOT + slot], srow);
                atomicAdd(&part[(size_t)((chbase + m0 + m_l)*2+1)*NSLOT + slot], qrow);
            }
            if (mxmnout){
                unsigned pk[2];
                #pragma unroll
                for (int h=0;h<2;h++){
                    float mxl = fmaxf(vr4[2*h], vr4[2*h+1]);
                    float mnl = fminf(vr4[2*h], vr4[2*h+1]);
                    mxl = rowmax16(mxl);
                    mnl = rowmin16(mnl);
                    pk[h] = (unsigned)f2bfbits(mxl) | ((unsigned)f2bfbits(mnl)<<16);
                }
                if (col == 15){
                    int bsi = (n0>>5) + wn*2;
                    *reinterpret_cast<uint2*>(&mxmnout[(size_t)(m0+m_l)*4096 + bsi]) =
                        make_uint2(pk[0], pk[1]);
                }
            }
        }
    }
}

// ---- final: fused bn4-coef + BN4 + ReLU + maxpool via packed extrema ---------
__global__ __launch_bounds__(256) void final_kernel(const unsigned* __restrict__ mxmn4,
                                                    const float* __restrict__ part,
                                                    const float* __restrict__ g4,
                                                    const float* __restrict__ be4,
                                                    float* __restrict__ out){
    __shared__ float abS[2];
    const int t = threadIdx.x;
    const int c = (blockIdx.x >> 2) & 255;
    const int b = blockIdx.x >> 10;
    const int s = ((blockIdx.x & 3) << 8) | t;
    if (t < 64){
        float ss = part[(size_t)((768+c)*2+0)*NSLOT + t];
        float qq = part[(size_t)((768+c)*2+1)*NSLOT + t];
        ss = wave_sum_f32(ss);
        qq = wave_sum_f32(qq);
        if (t==0){
            const float inv = 1.0f/(float)NPOS_;
            float mean = ss*inv;
            float var  = qq*inv - mean*mean;
            float a = g4[c]*rsqrtf(var + BN_EPS_);
            abS[0] = a; abS[1] = be4[c] - mean*a;
        }
    }
    __syncthreads();
    const float a = abS[0], bb = abS[1];
    const int bsi = b*NS_ + s;
    unsigned v = mxmn4[(size_t)c*4096 + bsi];
    float x = (a >= 0.f) ? bits2f((us)(v & 0xFFFFu)) : bits2f((us)(v >> 16));
    out[(size_t)(b*256 + c)*NS_ + s] = fmaxf(fmaf(x, a, bb), 0.0f);
}

extern "C" void kernel_launch(void* const* d_in, const int* in_sizes, int n_in,
                              void* d_out, int out_size, void* d_ws, size_t ws_size,
                              hipStream_t stream) {
    const float* p   = (const float*)d_in[0];
    const float* f   = (const float*)d_in[1];
    const float* w1  = (const float*)d_in[2];
    const float* w2  = (const float*)d_in[3];
    const float* b2  = (const float*)d_in[4];
    const float* g2  = (const float*)d_in[5];
    const float* be2 = (const float*)d_in[6];
    const float* w3  = (const float*)d_in[7];
    const float* g3  = (const float*)d_in[8];
    const float* be3 = (const float*)d_in[9];
    const float* w4  = (const float*)d_in[10];
    const float* g4  = (const float*)d_in[11];
    const float* be4 = (const float*)d_in[12];

    // Workspace (~215 MB); aliases:
    //   mxmn2 (4 MB) aliases t3 -- read by xm (disp 2) BEFORE gemm128 writes t3 (disp 3)
    //   mxmn4 (4 MB) aliases z2 -- written by gemm7 (disp 6) AFTER z2's last read (disp 4)
    char* ws = (char*)d_ws;
    float*    W26   = (float*)(ws + 540672);        // 6 KB
    float2*   ab2   = (float2*)(ws + 555008);       // 2 KB
    float2*   ab3   = (float2*)(ws + 557056);       // 4 KB
    us*       whi3  = (us*)(ws + 561152);           // 512 KB
    us*       whi4  = (us*)(ws + 1609728);          // 256 KB
    float*    t3    = (float*)(ws + 2134016);       // 8 MB
    unsigned* mxmn2 = (unsigned*)(ws + 2134016);    // 4 MB (aliases t3)
    bf16*     z2    = (bf16*)(ws + 10522624);       // 64 MB
    unsigned* mxmn4 = (unsigned*)(ws + 10522624);   // 4 MB (aliases z2, post disp-4)
    bf16*     xm    = (bf16*)(ws + 77631488);       // 2 MB
    bf16*     z3    = (bf16*)(ws + 79728640);       // 128 MB (end 213946368)
    float*    part  = (float*)(ws + 213946368);     // 512 KB partial stats
    int*      prog  = (int*)(ws + 214470656);       // 16 KB progress words
    int*      w26flag = (int*)(ws + 214487040);     // 4 B

    float* out_cntrd = (float*)d_out;
    float* out_feat  = (float*)d_out + (size_t)B_*NS_*3;

    // 0: zero part + prog + w26flag in one capturable memset
    hipMemsetAsync(ws + 213946368, 0, 540676, stream);
    // 1: FPS producer + preps + convknn consumers
    mega_kernel<<<5637, 256, 0, stream>>>(p, f, out_cntrd, part, prog, w26flag,
                                          w1, w2, W26, b2,
                                          w3, whi3, w4, whi4, z2, mxmn2);
    // 2: xm = max_k relu(bn2(z2)) from packed extrema (+ fused bn2-coef -> ab2)
    xm_kernel<<<128, 256, 0, stream>>>(mxmn2, part, g2, be2, ab2, xm);
    // 3: t3 = w3[:, :256] @ xm   (64x128 tiles, full machine)
    gemm128<<<dim3(32,8), 256, 0, stream>>>(w3, 512, 0, xm, 512, 4096, 256, t3);
    // 4: z3 = w3[:, 256:] @ relu(bn2(z2)) + t3   (+ BN3 partial stats)
    gemm_mfma<<<dim3(4,1024), 256, 0, stream>>>(whi3, 512, 256, z2, 256, ab2, z3, t3, part, 256,
                                                nullptr);
    // 5: BN3 coefficients
    bn_coef<<<2, 256, 0, stream>>>(part, g3, be3, 256, 512, ab3);
    // 6: w4 @ relu(bn3(z3)) -> packed per-(c,bsi) max/min (+ BN4 partial stats)
    gemm_mfma<<<dim3(2,1024), 256, 0, stream>>>(whi4, 512, 0, z3, 512, ab3, nullptr, nullptr, part, 768,
                                                mxmn4);
    // 7: fused bn4-coef + BN4 + ReLU + maxpool -> out
    final_kernel<<<4096, 256, 0, stream>>>(mxmn4, part, g4, be4, out_feat);
}

// Round 9
// 1057.123 us; speedup vs baseline: 1.0026x; 1.0026x over previous
//
#include <hip/hip_runtime.h>
#include <hip/hip_bf16.h>

#define B_ 4
#define N_ 4096
#define NS_ 1024
#define KNN_ 32
#define NPOS_ 131072   /* B_*NS_*KNN_ */
#define BN_EPS_ 1e-5f

using bf16 = __hip_bfloat16;
typedef unsigned short us;
typedef __attribute__((ext_vector_type(8))) short short8;
typedef __attribute__((ext_vector_type(4))) float f32x4;
typedef unsigned long long ull;

__device__ __forceinline__ float bf2f(bf16 h){ return __bfloat162float(h); }
__device__ __forceinline__ us f2bfbits(float x){
    bf16 h = __float2bfloat16(x);
    return *reinterpret_cast<us*>(&h);
}
__device__ __forceinline__ float bits2f(us u){
    unsigned v = ((unsigned)u)<<16; return __uint_as_float(v);
}
__device__ __forceinline__ void unpack8(uint4 v, float* f){
    f[0]=__uint_as_float((v.x&0xFFFFu)<<16); f[1]=__uint_as_float(v.x&0xFFFF0000u);
    f[2]=__uint_as_float((v.y&0xFFFFu)<<16); f[3]=__uint_as_float(v.y&0xFFFF0000u);
    f[4]=__uint_as_float((v.z&0xFFFFu)<<16); f[5]=__uint_as_float(v.z&0xFFFF0000u);
    f[6]=__uint_as_float((v.w&0xFFFFu)<<16); f[7]=__uint_as_float(v.w&0xFFFF0000u);
}
__device__ __forceinline__ uint4 pack8(const float* f){
    uint4 v;
    v.x = (unsigned)f2bfbits(f[0]) | ((unsigned)f2bfbits(f[1])<<16);
    v.y = (unsigned)f2bfbits(f[2]) | ((unsigned)f2bfbits(f[3])<<16);
    v.z = (unsigned)f2bfbits(f[4]) | ((unsigned)f2bfbits(f[5])<<16);
    v.w = (unsigned)f2bfbits(f[6]) | ((unsigned)f2bfbits(f[7])<<16);
    return v;
}
__device__ __forceinline__ unsigned fmono(float v){
    unsigned u = __float_as_uint(v);
    return (u & 0x80000000u) ? ~u : (u | 0x80000000u);
}

// ---- DPP wave64 reductions ----
template<int CTRL, int ROWM>
__device__ __forceinline__ float dppmaxf(float x){
    int xi = __float_as_int(x);
    int yi = __builtin_amdgcn_update_dpp(xi, xi, CTRL, ROWM, 0xF, false);
    return fmaxf(x, __int_as_float(yi));
}
template<int CTRL, int ROWM>
__device__ __forceinline__ float dppminf(float x){
    int xi = __float_as_int(x);
    int yi = __builtin_amdgcn_update_dpp(xi, xi, CTRL, ROWM, 0xF, false);
    return fminf(x, __int_as_float(yi));
}
__device__ __forceinline__ float wave_max_f32(float x){
    x = dppmaxf<0x111,0xF>(x);
    x = dppmaxf<0x112,0xF>(x);
    x = dppmaxf<0x114,0xF>(x);
    x = dppmaxf<0x118,0xF>(x);
    x = dppmaxf<0x142,0xA>(x);
    x = dppmaxf<0x143,0xC>(x);
    return __int_as_float(__builtin_amdgcn_readlane(__float_as_int(x), 63));
}
__device__ __forceinline__ float wave_min_f32(float x){
    x = dppminf<0x111,0xF>(x);
    x = dppminf<0x112,0xF>(x);
    x = dppminf<0x114,0xF>(x);
    x = dppminf<0x118,0xF>(x);
    x = dppminf<0x142,0xA>(x);
    x = dppminf<0x143,0xC>(x);
    return __int_as_float(__builtin_amdgcn_readlane(__float_as_int(x), 63));
}
// sum across each 16-lane DPP row; lane (lane&15)==15 holds row total
__device__ __forceinline__ float rowsum16(float x){
    x += __int_as_float(__builtin_amdgcn_update_dpp(0, __float_as_int(x), 0x111, 0xF, 0xF, true));
    x += __int_as_float(__builtin_amdgcn_update_dpp(0, __float_as_int(x), 0x112, 0xF, 0xF, true));
    x += __int_as_float(__builtin_amdgcn_update_dpp(0, __float_as_int(x), 0x114, 0xF, 0xF, true));
    x += __int_as_float(__builtin_amdgcn_update_dpp(0, __float_as_int(x), 0x118, 0xF, 0xF, true));
    return x;
}
// max/min across each 16-lane DPP row; lane (lane&15)==15 holds row result
__device__ __forceinline__ float rowmax16(float x){
    x = dppmaxf<0x111,0xF>(x);
    x = dppmaxf<0x112,0xF>(x);
    x = dppmaxf<0x114,0xF>(x);
    x = dppmaxf<0x118,0xF>(x);
    return x;
}
__device__ __forceinline__ float rowmin16(float x){
    x = dppminf<0x111,0xF>(x);
    x = dppminf<0x112,0xF>(x);
    x = dppminf<0x114,0xF>(x);
    x = dppminf<0x118,0xF>(x);
    return x;
}
// full 64-lane sum -> broadcast via readlane 63
__device__ __forceinline__ float wave_sum_f32(float x){
    x = rowsum16(x);
    x += __int_as_float(__builtin_amdgcn_update_dpp(0, __float_as_int(x), 0x142, 0xA, 0xF, false));
    x += __int_as_float(__builtin_amdgcn_update_dpp(0, __float_as_int(x), 0x143, 0xC, 0xF, false));
    return __int_as_float(__builtin_amdgcn_readlane(__float_as_int(x), 63));
}
__device__ __forceinline__ float max16(const float* v){
    float a = fmaxf(fmaxf(fmaxf(v[0],v[1]),v[2]),v[3]);
    float b = fmaxf(fmaxf(fmaxf(v[4],v[5]),v[6]),v[7]);
    float c = fmaxf(fmaxf(fmaxf(v[8],v[9]),v[10]),v[11]);
    float d = fmaxf(fmaxf(fmaxf(v[12],v[13]),v[14]),v[15]);
    return fmaxf(fmaxf(a,b), fmaxf(c,d));
}
__device__ __forceinline__ float min16(const float* v){
    float a = fminf(fminf(fminf(v[0],v[1]),v[2]),v[3]);
    float b = fminf(fminf(fminf(v[4],v[5]),v[6]),v[7]);
    float c = fminf(fminf(fminf(v[8],v[9]),v[10]),v[11]);
    float d = fminf(fminf(fminf(v[12],v[13]),v[14]),v[15]);
    return fminf(fminf(a,b), fminf(c,d));
}

// Partial-stats layout: part[(ch*2+k)*64 + slot], ch in [0,1024)
#define NSLOT 64

// -------------------- BN coef from 64-slot partials (bn2, bn3) ---------------
__global__ __launch_bounds__(256) void bn_coef(const float* __restrict__ part,
                                               const float* __restrict__ g,
                                               const float* __restrict__ be,
                                               int chbase, int C,
                                               float2* __restrict__ ab){
    int c = blockIdx.x*256 + threadIdx.x;
    if (c < C){
        const float* ps = part + (size_t)(chbase+c)*2*NSLOT;
        float s = 0.f, q = 0.f;
        #pragma unroll 8
        for (int i=0;i<NSLOT;i++){ s += ps[i]; q += ps[NSLOT+i]; }
        const float inv = 1.0f/(float)NPOS_;
        float mean = s*inv;
        float var  = q*inv - mean*mean;
        float a = g[c]*rsqrtf(var + BN_EPS_);
        ab[c] = make_float2(a, be[c] - mean*a);
    }
}

// -------------------- mega: FPS producer + preps + convknn consumers ----------
// FPS body is the R0-proven form EXCEPT the in-loop barrier: __syncthreads()
// emits s_waitcnt vmcnt(0) lgkmcnt(0), forcing wave 0 to drain t0's 4
// outstanding device-scope stores (atomicExch + 3 cntrd) EVERY step (~500-900
// cy L2 round-trip on the critical path; ~45% of the measured 1580 cy/step).
// Replaced with lgkmcnt(0)-only + raw s_barrier + sched_barrier(0) (rule-18
// hoist guard): cross-wave data flows only through LDS (warr), so only lgkm
// needs draining; the globals stay in flight across the barrier. [R8: isolated
// test of the drain theory -- R3 tested it confounded with 3 other changes.]
__global__ __launch_bounds__(256) void mega_kernel(const float* __restrict__ p,
                                                   const float* __restrict__ f,
                                                   float* __restrict__ cntrd,
                                                   float* __restrict__ part,
                                                   int* __restrict__ prog,
                                                   int* __restrict__ w26flag,
                                                   const float* __restrict__ w1,
                                                   const float* __restrict__ w2,
                                                   float* __restrict__ W26,
                                                   const float* __restrict__ b2,
                                                   const float* __restrict__ w3,
                                                   us* __restrict__ whi3,
                                                   const float* __restrict__ w4,
                                                   us* __restrict__ whi4,
                                                   bf16* __restrict__ z2,
                                                   unsigned* __restrict__ mxmn2){
    __shared__ float4 pxyz[N_];
    __shared__ ull warr[2][4];
    __shared__ int knnS[32];
    __shared__ float Ws[6][256];
    __shared__ float xs[6][32];
    __shared__ int ciS;
    const int bid = blockIdx.x;
    const int t = threadIdx.x;
    const int lane = t & 63;
    const int wave = t >> 6;

    if (bid < 4){
        // ---------------- FPS producer ----------------
        const int b = bid;
        const float* pb = p + (size_t)b*N_*3;
        float rx[16], ry[16], rz[16], dist[16];
        #pragma unroll
        for (int j=0;j<16;j++){
            int i = t*16+j;
            float x = pb[i*3+0];
            float y = pb[i*3+1];
            float z = pb[i*3+2];
            rx[j]=x; ry[j]=y; rz[j]=z;
            pxyz[i] = make_float4(x,y,z,0.f);
            dist[j]=1e10f;
        }
        __syncthreads();
        float4 c = pxyz[0];
        if (t==0){
            atomicExch(&prog[b*NS_], 1);
            cntrd[(size_t)(b*NS_)*3+0] = c.x;
            cntrd[(size_t)(b*NS_)*3+1] = c.y;
            cntrd[(size_t)(b*NS_)*3+2] = c.z;
        }
        for (int s=1; s<NS_; s++){
            #pragma unroll
            for (int j=0;j<16;j++){
                float dx = __fsub_rn(rx[j],c.x);
                float dy = __fsub_rn(ry[j],c.y);
                float dz = __fsub_rn(rz[j],c.z);
                float d  = __fadd_rn(__fadd_rn(__fmul_rn(dx,dx),__fmul_rn(dy,dy)),__fmul_rn(dz,dz));
                dist[j] = fminf(dist[j], d);
            }
            float lmax = max16(dist);
            float wmax = wave_max_f32(lmax);
            unsigned msk = 0;
            #pragma unroll
            for (int j=0;j<16;j++) msk |= (dist[j]==wmax) ? (1u<<j) : 0u;
            ull ball = __ballot(msk != 0);
            int srclane = (int)__builtin_ctzll(ball);
            unsigned lmsk = (unsigned)__builtin_amdgcn_readlane((int)msk, srclane);
            int widx = (wave*64 + srclane)*16 + (int)__builtin_ctz(lmsk);
            if (lane==0)
                warr[s&1][wave] = ((ull)__float_as_uint(wmax)<<32) | (0xFFFFFFFFu - (unsigned)widx);
            // relaxed barrier: drain LDS only; t0's global stores stay in flight
            asm volatile("s_waitcnt lgkmcnt(0)" ::: "memory");
            __builtin_amdgcn_s_barrier();
            __builtin_amdgcn_sched_barrier(0);
            ull g0 = warr[s&1][0], g1 = warr[s&1][1], g2 = warr[s&1][2], g3 = warr[s&1][3];
            ull ga = g0 > g1 ? g0 : g1;
            ull gb = g2 > g3 ? g2 : g3;
            ull g  = ga > gb ? ga : gb;
            int cur = (int)(0xFFFFFFFFu - (unsigned)(g & 0xFFFFFFFFull));
            c = pxyz[cur];
            if (t==0){
                atomicExch(&prog[b*NS_+s], cur+1);
                cntrd[(size_t)(b*NS_+s)*3+0] = c.x;
                cntrd[(size_t)(b*NS_+s)*3+1] = c.y;
                cntrd[(size_t)(b*NS_+s)*3+2] = c.z;
            }
        }
        return;
    }
    if (bid == 4){
        float acc[6] = {0,0,0,0,0,0};
        for (int k=0;k<256;k++){
            float w2v = w2[t*256+k];
            #pragma unroll
            for (int j=0;j<6;j++) acc[j] = fmaf(w2v, w1[k*6+j], acc[j]);
        }
        #pragma unroll
        for (int j=0;j<6;j++) W26[j*256+t] = acc[j];
        __syncthreads();
        if (t==0){ __threadfence(); atomicExch(w26flag, 1); }
        return;
    }
    if (bid < 1029){              // cast w3 -> bf16
        int i = (bid-5)*256 + t;
        whi3[i] = f2bfbits(w3[i]);
        return;
    }
    if (bid < 1541){              // cast w4 -> bf16
        int i = (bid-1029)*256 + t;
        whi4[i] = f2bfbits(w4[i]);
        return;
    }
    // ---------------- convknn worker ----------------
    const int wid = bid - 1541;
    const int b = wid & 3;
    const int si = wid >> 2;
    const int sidx = b*NS_ + si;
    const float* pb = p + (size_t)b*N_*3;
    if (t == 0){
        int v;
        while ((v = atomicAdd(&prog[sidx], 0)) == 0) { __builtin_amdgcn_s_sleep(8); }
        ciS = v - 1;
    }
    __syncthreads();
    const int ci = ciS;
    float cx = pb[ci*3+0];
    float cy = pb[ci*3+1];
    float cz = pb[ci*3+2];
    float c2 = __fadd_rn(__fadd_rn(__fmul_rn(cx,cx),__fmul_rn(cy,cy)),__fmul_rn(cz,cz));
    float d2[16];
    #pragma unroll
    for (int j=0;j<16;j++){
        int i = t*16+j;
        float x = pb[i*3+0];
        float y = pb[i*3+1];
        float z = pb[i*3+2];
        float p2 = __fadd_rn(__fadd_rn(__fmul_rn(x,x),__fmul_rn(y,y)),__fmul_rn(z,z));
        float dot= __fadd_rn(__fadd_rn(__fmul_rn(cx,x),__fmul_rn(cy,y)),__fmul_rn(cz,z));
        d2[j] = __fsub_rn(__fadd_rn(c2,p2), __fmul_rn(2.0f,dot));
    }
    for (int it=0; it<KNN_; it++){
        float lmin = min16(d2);
        float wmin = wave_min_f32(lmin);
        unsigned msk = 0;
        #pragma unroll
        for (int j=0;j<16;j++) msk |= (d2[j]==wmin) ? (1u<<j) : 0u;
        ull ball = __ballot(msk != 0);
        int srclane = (int)__builtin_ctzll(ball);
        unsigned lmsk = (unsigned)__builtin_amdgcn_readlane((int)msk, srclane);
        int widx = (wave*64 + srclane)*16 + (int)__builtin_ctz(lmsk);
        if (lane==0)
            warr[it&1][wave] = ((ull)fmono(wmin)<<32) | (unsigned)widx;
        __syncthreads();
        ull g0 = warr[it&1][0], g1 = warr[it&1][1], g2 = warr[it&1][2], g3 = warr[it&1][3];
        ull ga = g0 < g1 ? g0 : g1;
        ull gb = g2 < g3 ? g2 : g3;
        ull g  = ga < gb ? ga : gb;
        int idx = (int)(g & 0xFFFFFFFFull);
        if ((idx>>4)==t) d2[idx & 15] = INFINITY;
        if (t==0) knnS[it] = idx;
    }
    if (t == 0){ while (atomicAdd(w26flag, 0) == 0) { __builtin_amdgcn_s_sleep(8); } __threadfence(); }
    __syncthreads();
    #pragma unroll
    for (int r=0;r<6;r++) Ws[r][t] = W26[r*256+t];
    if (t < 32){
        int i = knnS[t];
        const float* fb = f + (size_t)b*3*N_;
        xs[0][t] = pb[i*3+0];
        xs[1][t] = pb[i*3+1];
        xs[2][t] = pb[i*3+2];
        xs[3][t] = fb[0*N_+i];
        xs[4][t] = fb[1*N_+i];
        xs[5][t] = fb[2*N_+i];
    }
    __syncthreads();
    float w0=Ws[0][t], w1v=Ws[1][t], w2v=Ws[2][t], w3v=Ws[3][t], w4v=Ws[4][t], w5v=Ws[5][t];
    float bias = b2[t];
    bf16* zrow = z2 + (size_t)t*NPOS_ + (size_t)sidx*KNN_;
    float ssum = 0.f, sq = 0.f;
    float mxv = -3.4e38f, mnv = 3.4e38f;   // per-(c,sidx) extrema of bf16(z2)
    for (int k0=0;k0<32;k0+=8){
        float y[8];
        #pragma unroll
        for (int u=0;u<8;u++){
            int k = k0+u;
            float acc = bias;
            acc = fmaf(w0, xs[0][k], acc);
            acc = fmaf(w1v,xs[1][k], acc);
            acc = fmaf(w2v,xs[2][k], acc);
            acc = fmaf(w3v,xs[3][k], acc);
            acc = fmaf(w4v,xs[4][k], acc);
            acc = fmaf(w5v,xs[5][k], acc);
            float vr = bits2f(f2bfbits(acc));
            ssum += vr; sq = fmaf(vr, vr, sq);
            mxv = fmaxf(mxv, vr); mnv = fminf(mnv, vr);
            y[u] = acc;
        }
        *reinterpret_cast<uint4*>(zrow + k0) = pack8(y);
    }
    // packed extrema, [sidx][c] layout: each worker writes its own 1KB run
    mxmn2[(size_t)sidx*256 + t] = (unsigned)f2bfbits(mxv) | ((unsigned)f2bfbits(mnv)<<16);
    const int slot = wid & (NSLOT-1);
    atomicAdd(&part[(size_t)(t*2+0)*NSLOT + slot], ssum);
    atomicAdd(&part[(size_t)(t*2+1)*NSLOT + slot], sq);
}

// -------- xm = max over K of relu(a*x+b) via packed per-(bs,c) extrema --------
// max_k relu(a*x_k+b) = relu(a*mx+b) if a>=0 else relu(a*mn+b)  (monotone fmaf)
// Block = 32 bs x 256 c; thread t owns channel c=t, writes 64B (full line) runs.
__global__ __launch_bounds__(256) void xm_kernel(const unsigned* __restrict__ mxmn2,
                                                 const float2* __restrict__ ab,
                                                 bf16* __restrict__ xm){
    const int t = threadIdx.x;
    const int bs0 = blockIdx.x * 32;
    float2 s = ab[t];
    us y[32];
    #pragma unroll
    for (int i=0;i<32;i++){
        unsigned v = mxmn2[(size_t)(bs0+i)*256 + t];
        float x = (s.x >= 0.f) ? bits2f((us)(v & 0xFFFFu)) : bits2f((us)(v >> 16));
        y[i] = f2bfbits(fmaxf(fmaf(x, s.x, s.y), 0.0f));
    }
    uint4* dst = reinterpret_cast<uint4*>(reinterpret_cast<us*>(xm) + (size_t)t*4096 + bs0);
    const uint4* src = reinterpret_cast<const uint4*>(y);
    dst[0]=src[0]; dst[1]=src[1]; dst[2]=src[2]; dst[3]=src[3];
}

// -------------------- small fp32 GEMM (t3 only) --------------------
__global__ __launch_bounds__(256) void gemm128(const float* __restrict__ A, int lda, int aoff,
                                               const bf16* __restrict__ B,
                                               int M, int N, int K,
                                               float* __restrict__ Cf){
    __shared__ float As[16][128];
    __shared__ float Bs[16][128];
    const int tid = threadIdx.x;
    const int tx = tid & 15, ty = tid >> 4;
    const int m0 = blockIdx.y*128, n0 = blockIdx.x*128;
    float acc[8][8];
    #pragma unroll
    for (int i=0;i<8;i++)
        #pragma unroll
        for (int j=0;j<8;j++) acc[i][j]=0.f;
    const int arow = tid >> 1, akg = tid & 1;
    const int bkk = tid >> 4, bng = tid & 15;
    for (int k0=0;k0<K;k0+=16){
        const float* aptr = A + (size_t)(m0+arow)*lda + aoff + k0 + akg*8;
        float4 a0 = *reinterpret_cast<const float4*>(aptr);
        float4 a1 = *reinterpret_cast<const float4*>(aptr+4);
        As[akg*8+0][arow]=a0.x; As[akg*8+1][arow]=a0.y;
        As[akg*8+2][arow]=a0.z; As[akg*8+3][arow]=a0.w;
        As[akg*8+4][arow]=a1.x; As[akg*8+5][arow]=a1.y;
        As[akg*8+6][arow]=a1.z; As[akg*8+7][arow]=a1.w;
        uint4 bv = *reinterpret_cast<const uint4*>(B + (size_t)(k0+bkk)*N + n0 + bng*8);
        float bf[8]; unpack8(bv, bf);
        *reinterpret_cast<float4*>(&Bs[bkk][bng*8+0]) = make_float4(bf[0],bf[1],bf[2],bf[3]);
        *reinterpret_cast<float4*>(&Bs[bkk][bng*8+4]) = make_float4(bf[4],bf[5],bf[6],bf[7]);
        __syncthreads();
        #pragma unroll
        for (int kk=0;kk<16;kk++){
            float a[8], b[8];
            *reinterpret_cast<float4*>(&a[0]) = *reinterpret_cast<float4*>(&As[kk][ty*8+0]);
            *reinterpret_cast<float4*>(&a[4]) = *reinterpret_cast<float4*>(&As[kk][ty*8+4]);
            *reinterpret_cast<float4*>(&b[0]) = *reinterpret_cast<float4*>(&Bs[kk][tx*8+0]);
            *reinterpret_cast<float4*>(&b[4]) = *reinterpret_cast<float4*>(&Bs[kk][tx*8+4]);
            #pragma unroll
            for (int i=0;i<8;i++)
                #pragma unroll
                for (int j=0;j<8;j++)
                    acc[i][j] = fmaf(a[i], b[j], acc[i][j]);
        }
        __syncthreads();
    }
    const int n = n0 + tx*8;
    #pragma unroll
    for (int i=0;i<8;i++){
        int m = m0 + ty*8 + i;
        *reinterpret_cast<float4*>(Cf + (size_t)m*N + n + 0) = make_float4(acc[i][0],acc[i][1],acc[i][2],acc[i][3]);
        *reinterpret_cast<float4*>(Cf + (size_t)m*N + n + 4) = make_float4(acc[i][4],acc[i][5],acc[i][6],acc[i][7]);
    }
}

// -------------------- MFMA GEMM: LDS-staged bf16 A, fused-BN B, fused stats ---
// When mxmnout!=nullptr: do NOT write the dense output; instead emit packed
// per-(row,sidx) max/min over the 32 k-columns (pool fusion for final maxpool).
//
// T1 XCD swizzle: same-n M-tile groups made consecutive-on-one-XCD.
#define LDK 40
__global__ __launch_bounds__(256) void gemm_mfma(const us* __restrict__ Whi,
                                                 int ldw, int aoff,
                                                 const bf16* __restrict__ act, int K,
                                                 const float2* __restrict__ ab,
                                                 bf16* __restrict__ out,
                                                 const float* __restrict__ t3,
                                                 float* __restrict__ part, int chbase,
                                                 unsigned* __restrict__ mxmnout){
    __shared__ __align__(16) us AsH[128*LDK];
    __shared__ __align__(16) us Bs [128*LDK];
    __shared__ float t3s[128][4];
    const us* actu = reinterpret_cast<const us*>(act);
    const int t = threadIdx.x;
    // ---- XCD-aware tile assignment (bijective remap of the linear id) ----
    const int nx  = gridDim.x;
    const int nwg = nx * gridDim.y;
    const int hid = blockIdx.y * nx + blockIdx.x;
    const int q8  = nwg >> 3;
    const int logical = (hid & 7) * q8 + (hid >> 3);
    const int mi = logical % nx;
    const int ni = logical / nx;
    const int m0 = mi*128, n0 = ni*128;
    const int wave = t>>6, lane = t&63;
    const int wm = wave>>1, wn = wave&1;
    const int q = lane>>4, col = lane&15;

    if (t3 && t < 128){
        const float* src = t3 + (size_t)(m0+t)*4096 + (n0>>5);
        t3s[t][0]=src[0]; t3s[t][1]=src[1]; t3s[t][2]=src[2]; t3s[t][3]=src[3];
    }

    f32x4 acc[4][4];
    #pragma unroll
    for (int i=0;i<4;i++)
        #pragma unroll
        for (int j=0;j<4;j++) acc[i][j] = (f32x4){0.f,0.f,0.f,0.f};

    const int ar = t>>1, ah = t&1;
    const int bn = t&127, bh = t>>7;

    for (int k0=0;k0<K;k0+=32){
        const us* sh = Whi + (size_t)(m0+ar)*ldw + aoff + k0 + ah*16;
        uint4 h0 = *reinterpret_cast<const uint4*>(sh);
        uint4 h1 = *reinterpret_cast<const uint4*>(sh+8);
        *reinterpret_cast<uint4*>(&AsH[ar*LDK + ah*16 + 0]) = h0;
        *reinterpret_cast<uint4*>(&AsH[ar*LDK + ah*16 + 8]) = h1;
        us bvals[16];
        #pragma unroll
        for (int j=0;j<16;j++){
            int k = k0 + bh*16 + j;
            float x = bits2f(actu[(size_t)k*NPOS_ + n0 + bn]);
            float2 s = ab[k];
            bvals[j] = f2bfbits(fmaxf(fmaf(x, s.x, s.y), 0.0f));
        }
        *reinterpret_cast<uint4*>(&Bs[bn*LDK + bh*16 + 0]) = *reinterpret_cast<uint4*>(&bvals[0]);
        *reinterpret_cast<uint4*>(&Bs[bn*LDK + bh*16 + 8]) = *reinterpret_cast<uint4*>(&bvals[8]);
        __syncthreads();
        short8 bf[4], afh[4];
        #pragma unroll
        for (int tn=0;tn<4;tn++)
            bf[tn] = *reinterpret_cast<const short8*>(&Bs[(wn*64+tn*16+col)*LDK + q*8]);
        #pragma unroll
        for (int tm=0;tm<4;tm++)
            afh[tm] = *reinterpret_cast<const short8*>(&AsH[(wm*64+tm*16+col)*LDK + q*8]);
        #pragma unroll
        for (int tm=0;tm<4;tm++)
            #pragma unroll
            for (int tn=0;tn<4;tn++)
                acc[tm][tn] = __builtin_amdgcn_mfma_f32_16x16x32_bf16(afh[tm], bf[tn], acc[tm][tn], 0, 0, 0);
        __syncthreads();
    }
    const int slot = ni & (NSLOT-1);
    #pragma unroll
    for (int tm=0;tm<4;tm++){
        #pragma unroll
        for (int r=0;r<4;r++){
            int m_l = wm*64 + tm*16 + q*4 + r;
            float srow = 0.f, qrow = 0.f;
            float vr4[4];
            #pragma unroll
            for (int tn=0;tn<4;tn++){
                int n_l = wn*64 + tn*16 + col;
                float vv = acc[tm][tn][r];
                if (t3) vv += t3s[m_l][n_l>>5];
                us hb = f2bfbits(vv);
                if (!mxmnout)
                    reinterpret_cast<us*>(out)[(size_t)(m0+m_l)*NPOS_ + n0 + n_l] = hb;
                float vr = bits2f(hb);
                vr4[tn] = vr;
                srow += vr; qrow = fmaf(vr, vr, qrow);
            }
            srow = rowsum16(srow);
            qrow = rowsum16(qrow);
            if (col == 15){
                atomicAdd(&part[(size_t)((chbase + m0 + m_l)*2+0)*NSLOT + slot], srow);
                atomicAdd(&part[(size_t)((chbase + m0 + m_l)*2+1)*NSLOT + slot], qrow);
            }
            if (mxmnout){
                unsigned pk[2];
                #pragma unroll
                for (int h=0;h<2;h++){
                    float mxl = fmaxf(vr4[2*h], vr4[2*h+1]);
                    float mnl = fminf(vr4[2*h], vr4[2*h+1]);
                    mxl = rowmax16(mxl);
                    mnl = rowmin16(mnl);
                    pk[h] = (unsigned)f2bfbits(mxl) | ((unsigned)f2bfbits(mnl)<<16);
                }
                if (col == 15){
                    int bsi = (n0>>5) + wn*2;
                    *reinterpret_cast<uint2*>(&mxmnout[(size_t)(m0+m_l)*4096 + bsi]) =
                        make_uint2(pk[0], pk[1]);
                }
            }
        }
    }
}

// ---- final: fused bn4-coef + BN4 + ReLU + maxpool via packed extrema ---------
__global__ __launch_bounds__(256) void final_kernel(const unsigned* __restrict__ mxmn4,
                                                    const float* __restrict__ part,
                                                    const float* __restrict__ g4,
                                                    const float* __restrict__ be4,
                                                    float* __restrict__ out){
    __shared__ float abS[2];
    const int t = threadIdx.x;
    const int c = (blockIdx.x >> 2) & 255;
    const int b = blockIdx.x >> 10;
    const int s = ((blockIdx.x & 3) << 8) | t;
    if (t < 64){
        float ss = part[(size_t)((768+c)*2+0)*NSLOT + t];
        float qq = part[(size_t)((768+c)*2+1)*NSLOT + t];
        ss = wave_sum_f32(ss);
        qq = wave_sum_f32(qq);
        if (t==0){
            const float inv = 1.0f/(float)NPOS_;
            float mean = ss*inv;
            float var  = qq*inv - mean*mean;
            float a = g4[c]*rsqrtf(var + BN_EPS_);
            abS[0] = a; abS[1] = be4[c] - mean*a;
        }
    }
    __syncthreads();
    const float a = abS[0], bb = abS[1];
    const int bsi = b*NS_ + s;
    unsigned v = mxmn4[(size_t)c*4096 + bsi];
    float x = (a >= 0.f) ? bits2f((us)(v & 0xFFFFu)) : bits2f((us)(v >> 16));
    out[(size_t)(b*256 + c)*NS_ + s] = fmaxf(fmaf(x, a, bb), 0.0f);
}

extern "C" void kernel_launch(void* const* d_in, const int* in_sizes, int n_in,
                              void* d_out, int out_size, void* d_ws, size_t ws_size,
                              hipStream_t stream) {
    const float* p   = (const float*)d_in[0];
    const float* f   = (const float*)d_in[1];
    const float* w1  = (const float*)d_in[2];
    const float* w2  = (const float*)d_in[3];
    const float* b2  = (const float*)d_in[4];
    const float* g2  = (const float*)d_in[5];
    const float* be2 = (const float*)d_in[6];
    const float* w3  = (const float*)d_in[7];
    const float* g3  = (const float*)d_in[8];
    const float* be3 = (const float*)d_in[9];
    const float* w4  = (const float*)d_in[10];
    const float* g4  = (const float*)d_in[11];
    const float* be4 = (const float*)d_in[12];

    // Workspace (~215 MB); aliases:
    //   mxmn2 (4 MB) aliases t3 -- read by xm (disp 3) BEFORE gemm128 writes t3 (disp 4)
    //   mxmn4 (4 MB) aliases z2 -- written by gemm7 (disp 7) AFTER z2's last read (disp 5)
    char* ws = (char*)d_ws;
    float*    W26   = (float*)(ws + 540672);        // 6 KB
    float2*   ab2   = (float2*)(ws + 555008);       // 2 KB
    float2*   ab3   = (float2*)(ws + 557056);       // 4 KB
    us*       whi3  = (us*)(ws + 561152);           // 512 KB
    us*       whi4  = (us*)(ws + 1609728);          // 256 KB
    float*    t3    = (float*)(ws + 2134016);       // 8 MB
    unsigned* mxmn2 = (unsigned*)(ws + 2134016);    // 4 MB (aliases t3)
    bf16*     z2    = (bf16*)(ws + 10522624);       // 64 MB
    unsigned* mxmn4 = (unsigned*)(ws + 10522624);   // 4 MB (aliases z2, post disp-5)
    bf16*     xm    = (bf16*)(ws + 77631488);       // 2 MB
    bf16*     z3    = (bf16*)(ws + 79728640);       // 128 MB (end 213946368)
    float*    part  = (float*)(ws + 213946368);     // 512 KB partial stats
    int*      prog  = (int*)(ws + 214470656);       // 16 KB progress words
    int*      w26flag = (int*)(ws + 214487040);     // 4 B

    float* out_cntrd = (float*)d_out;
    float* out_feat  = (float*)d_out + (size_t)B_*NS_*3;

    // 0: zero part + prog + w26flag in one capturable memset
    hipMemsetAsync(ws + 213946368, 0, 540676, stream);
    // 1: FPS producer + preps + convknn consumers
    mega_kernel<<<5637, 256, 0, stream>>>(p, f, out_cntrd, part, prog, w26flag,
                                          w1, w2, W26, b2,
                                          w3, whi3, w4, whi4, z2, mxmn2);
    // 2: BN2 coefficients
    bn_coef<<<1, 256, 0, stream>>>(part, g2, be2, 0, 256, ab2);
    // 3: xm = max_k relu(bn2(z2)) from packed extrema
    xm_kernel<<<128, 256, 0, stream>>>(mxmn2, ab2, xm);
    // 4: t3 = w3[:, :256] @ xm
    gemm128<<<dim3(32,4), 256, 0, stream>>>(w3, 512, 0, xm, 512, 4096, 256, t3);
    // 5: z3 = w3[:, 256:] @ relu(bn2(z2)) + t3   (+ BN3 partial stats)
    gemm_mfma<<<dim3(4,1024), 256, 0, stream>>>(whi3, 512, 256, z2, 256, ab2, z3, t3, part, 256,
                                                nullptr);
    // 6: BN3 coefficients
    bn_coef<<<2, 256, 0, stream>>>(part, g3, be3, 256, 512, ab3);
    // 7: w4 @ relu(bn3(z3)) -> packed per-(c,bsi) max/min (+ BN4 partial stats)
    gemm_mfma<<<dim3(2,1024), 256, 0, stream>>>(whi4, 512, 0, z3, 512, ab3, nullptr, nullptr, part, 768,
                                                mxmn4);
    // 8: fused bn4-coef + BN4 + ReLU + maxpool -> out
    final_kernel<<<4096, 256, 0, stream>>>(mxmn4, part, g4, be4, out_feat);
}

// Round 10
// 1048.003 us; speedup vs baseline: 1.0113x; 1.0087x over previous
//
#include <hip/hip_runtime.h>
#include <hip/hip_bf16.h>

#define B_ 4
#define N_ 4096
#define NS_ 1024
#define KNN_ 32
#define NPOS_ 131072   /* B_*NS_*KNN_ */
#define BN_EPS_ 1e-5f

using bf16 = __hip_bfloat16;
typedef unsigned short us;
typedef __attribute__((ext_vector_type(8))) short short8;
typedef __attribute__((ext_vector_type(4))) float f32x4;
typedef unsigned long long ull;

__device__ __forceinline__ float bf2f(bf16 h){ return __bfloat162float(h); }
__device__ __forceinline__ us f2bfbits(float x){
    bf16 h = __float2bfloat16(x);
    return *reinterpret_cast<us*>(&h);
}
__device__ __forceinline__ float bits2f(us u){
    unsigned v = ((unsigned)u)<<16; return __uint_as_float(v);
}
__device__ __forceinline__ void unpack8(uint4 v, float* f){
    f[0]=__uint_as_float((v.x&0xFFFFu)<<16); f[1]=__uint_as_float(v.x&0xFFFF0000u);
    f[2]=__uint_as_float((v.y&0xFFFFu)<<16); f[3]=__uint_as_float(v.y&0xFFFF0000u);
    f[4]=__uint_as_float((v.z&0xFFFFu)<<16); f[5]=__uint_as_float(v.z&0xFFFF0000u);
    f[6]=__uint_as_float((v.w&0xFFFFu)<<16); f[7]=__uint_as_float(v.w&0xFFFF0000u);
}
__device__ __forceinline__ uint4 pack8(const float* f){
    uint4 v;
    v.x = (unsigned)f2bfbits(f[0]) | ((unsigned)f2bfbits(f[1])<<16);
    v.y = (unsigned)f2bfbits(f[2]) | ((unsigned)f2bfbits(f[3])<<16);
    v.z = (unsigned)f2bfbits(f[4]) | ((unsigned)f2bfbits(f[5])<<16);
    v.w = (unsigned)f2bfbits(f[6]) | ((unsigned)f2bfbits(f[7])<<16);
    return v;
}
__device__ __forceinline__ unsigned fmono(float v){
    unsigned u = __float_as_uint(v);
    return (u & 0x80000000u) ? ~u : (u | 0x80000000u);
}

// ---- DPP wave64 reductions ----
template<int CTRL, int ROWM>
__device__ __forceinline__ float dppmaxf(float x){
    int xi = __float_as_int(x);
    int yi = __builtin_amdgcn_update_dpp(xi, xi, CTRL, ROWM, 0xF, false);
    return fmaxf(x, __int_as_float(yi));
}
template<int CTRL, int ROWM>
__device__ __forceinline__ float dppminf(float x){
    int xi = __float_as_int(x);
    int yi = __builtin_amdgcn_update_dpp(xi, xi, CTRL, ROWM, 0xF, false);
    return fminf(x, __int_as_float(yi));
}
__device__ __forceinline__ float wave_max_f32(float x){
    x = dppmaxf<0x111,0xF>(x);
    x = dppmaxf<0x112,0xF>(x);
    x = dppmaxf<0x114,0xF>(x);
    x = dppmaxf<0x118,0xF>(x);
    x = dppmaxf<0x142,0xA>(x);
    x = dppmaxf<0x143,0xC>(x);
    return __int_as_float(__builtin_amdgcn_readlane(__float_as_int(x), 63));
}
__device__ __forceinline__ float wave_min_f32(float x){
    x = dppminf<0x111,0xF>(x);
    x = dppminf<0x112,0xF>(x);
    x = dppminf<0x114,0xF>(x);
    x = dppminf<0x118,0xF>(x);
    x = dppminf<0x142,0xA>(x);
    x = dppminf<0x143,0xC>(x);
    return __int_as_float(__builtin_amdgcn_readlane(__float_as_int(x), 63));
}
// sum across each 16-lane DPP row; lane (lane&15)==15 holds row total
__device__ __forceinline__ float rowsum16(float x){
    x += __int_as_float(__builtin_amdgcn_update_dpp(0, __float_as_int(x), 0x111, 0xF, 0xF, true));
    x += __int_as_float(__builtin_amdgcn_update_dpp(0, __float_as_int(x), 0x112, 0xF, 0xF, true));
    x += __int_as_float(__builtin_amdgcn_update_dpp(0, __float_as_int(x), 0x114, 0xF, 0xF, true));
    x += __int_as_float(__builtin_amdgcn_update_dpp(0, __float_as_int(x), 0x118, 0xF, 0xF, true));
    return x;
}
// max/min across each 16-lane DPP row; lane (lane&15)==15 holds row result
__device__ __forceinline__ float rowmax16(float x){
    x = dppmaxf<0x111,0xF>(x);
    x = dppmaxf<0x112,0xF>(x);
    x = dppmaxf<0x114,0xF>(x);
    x = dppmaxf<0x118,0xF>(x);
    return x;
}
__device__ __forceinline__ float rowmin16(float x){
    x = dppminf<0x111,0xF>(x);
    x = dppminf<0x112,0xF>(x);
    x = dppminf<0x114,0xF>(x);
    x = dppminf<0x118,0xF>(x);
    return x;
}
// full 64-lane sum -> broadcast via readlane 63
__device__ __forceinline__ float wave_sum_f32(float x){
    x = rowsum16(x);
    x += __int_as_float(__builtin_amdgcn_update_dpp(0, __float_as_int(x), 0x142, 0xA, 0xF, false));
    x += __int_as_float(__builtin_amdgcn_update_dpp(0, __float_as_int(x), 0x143, 0xC, 0xF, false));
    return __int_as_float(__builtin_amdgcn_readlane(__float_as_int(x), 63));
}
__device__ __forceinline__ float max16(const float* v){
    float a = fmaxf(fmaxf(fmaxf(v[0],v[1]),v[2]),v[3]);
    float b = fmaxf(fmaxf(fmaxf(v[4],v[5]),v[6]),v[7]);
    float c = fmaxf(fmaxf(fmaxf(v[8],v[9]),v[10]),v[11]);
    float d = fmaxf(fmaxf(fmaxf(v[12],v[13]),v[14]),v[15]);
    return fmaxf(fmaxf(a,b), fmaxf(c,d));
}
__device__ __forceinline__ float min16(const float* v){
    float a = fminf(fminf(fminf(v[0],v[1]),v[2]),v[3]);
    float b = fminf(fminf(fminf(v[4],v[5]),v[6]),v[7]);
    float c = fminf(fminf(fminf(v[8],v[9]),v[10]),v[11]);
    float d = fminf(fminf(fminf(v[12],v[13]),v[14]),v[15]);
    return fminf(fminf(a,b), fminf(c,d));
}

// Partial-stats layout: part[(ch*2+k)*64 + slot], ch in [0,1024)
#define NSLOT 64

// -------------------- BN coef from 64-slot partials (bn2, bn3) ---------------
__global__ __launch_bounds__(256) void bn_coef(const float* __restrict__ part,
                                               const float* __restrict__ g,
                                               const float* __restrict__ be,
                                               int chbase, int C,
                                               float2* __restrict__ ab){
    int c = blockIdx.x*256 + threadIdx.x;
    if (c < C){
        const float* ps = part + (size_t)(chbase+c)*2*NSLOT;
        float s = 0.f, q = 0.f;
        #pragma unroll 8
        for (int i=0;i<NSLOT;i++){ s += ps[i]; q += ps[NSLOT+i]; }
        const float inv = 1.0f/(float)NPOS_;
        float mean = s*inv;
        float var  = q*inv - mean*mean;
        float a = g[c]*rsqrtf(var + BN_EPS_);
        ab[c] = make_float2(a, be[c] - mean*a);
    }
}

// -------------------- mega: FPS producer + preps + convknn consumers ----------
// FPS body is the R0-proven form (fastest measured). R1-R4 and R8 established
// empirically that setprio / CU-exclusivity / relaxed barriers (isolated, R8) /
// deferred writes / dual-batch ILP ALL regress it -- do not touch this loop.
// Its ~655 ns/step is the intrinsic serial-dependency latency of the argmax
// chain (0% MFMA, 23% VALU, 3% HBM: latency-bound, not resource-bound).
__global__ __launch_bounds__(256) void mega_kernel(const float* __restrict__ p,
                                                   const float* __restrict__ f,
                                                   float* __restrict__ cntrd,
                                                   float* __restrict__ part,
                                                   int* __restrict__ prog,
                                                   int* __restrict__ w26flag,
                                                   const float* __restrict__ w1,
                                                   const float* __restrict__ w2,
                                                   float* __restrict__ W26,
                                                   const float* __restrict__ b2,
                                                   const float* __restrict__ w3,
                                                   us* __restrict__ whi3,
                                                   const float* __restrict__ w4,
                                                   us* __restrict__ whi4,
                                                   bf16* __restrict__ z2,
                                                   unsigned* __restrict__ mxmn2){
    __shared__ float4 pxyz[N_];
    __shared__ ull warr[2][4];
    __shared__ int knnS[32];
    __shared__ float Ws[6][256];
    __shared__ float xs[6][32];
    __shared__ int ciS;
    const int bid = blockIdx.x;
    const int t = threadIdx.x;
    const int lane = t & 63;
    const int wave = t >> 6;

    if (bid < 4){
        // ---------------- FPS producer (proven R0 body -- do not modify) -----
        const int b = bid;
        const float* pb = p + (size_t)b*N_*3;
        float rx[16], ry[16], rz[16], dist[16];
        #pragma unroll
        for (int j=0;j<16;j++){
            int i = t*16+j;
            float x = pb[i*3+0];
            float y = pb[i*3+1];
            float z = pb[i*3+2];
            rx[j]=x; ry[j]=y; rz[j]=z;
            pxyz[i] = make_float4(x,y,z,0.f);
            dist[j]=1e10f;
        }
        __syncthreads();
        float4 c = pxyz[0];
        if (t==0){
            atomicExch(&prog[b*NS_], 1);
            cntrd[(size_t)(b*NS_)*3+0] = c.x;
            cntrd[(size_t)(b*NS_)*3+1] = c.y;
            cntrd[(size_t)(b*NS_)*3+2] = c.z;
        }
        for (int s=1; s<NS_; s++){
            #pragma unroll
            for (int j=0;j<16;j++){
                float dx = __fsub_rn(rx[j],c.x);
                float dy = __fsub_rn(ry[j],c.y);
                float dz = __fsub_rn(rz[j],c.z);
                float d  = __fadd_rn(__fadd_rn(__fmul_rn(dx,dx),__fmul_rn(dy,dy)),__fmul_rn(dz,dz));
                dist[j] = fminf(dist[j], d);
            }
            float lmax = max16(dist);
            float wmax = wave_max_f32(lmax);
            unsigned msk = 0;
            #pragma unroll
            for (int j=0;j<16;j++) msk |= (dist[j]==wmax) ? (1u<<j) : 0u;
            ull ball = __ballot(msk != 0);
            int srclane = (int)__builtin_ctzll(ball);
            unsigned lmsk = (unsigned)__builtin_amdgcn_readlane((int)msk, srclane);
            int widx = (wave*64 + srclane)*16 + (int)__builtin_ctz(lmsk);
            if (lane==0)
                warr[s&1][wave] = ((ull)__float_as_uint(wmax)<<32) | (0xFFFFFFFFu - (unsigned)widx);
            __syncthreads();
            ull g0 = warr[s&1][0], g1 = warr[s&1][1], g2 = warr[s&1][2], g3 = warr[s&1][3];
            ull ga = g0 > g1 ? g0 : g1;
            ull gb = g2 > g3 ? g2 : g3;
            ull g  = ga > gb ? ga : gb;
            int cur = (int)(0xFFFFFFFFu - (unsigned)(g & 0xFFFFFFFFull));
            c = pxyz[cur];
            if (t==0){
                atomicExch(&prog[b*NS_+s], cur+1);
                cntrd[(size_t)(b*NS_+s)*3+0] = c.x;
                cntrd[(size_t)(b*NS_+s)*3+1] = c.y;
                cntrd[(size_t)(b*NS_+s)*3+2] = c.z;
            }
        }
        return;
    }
    if (bid == 4){
        float acc[6] = {0,0,0,0,0,0};
        for (int k=0;k<256;k++){
            float w2v = w2[t*256+k];
            #pragma unroll
            for (int j=0;j<6;j++) acc[j] = fmaf(w2v, w1[k*6+j], acc[j]);
        }
        #pragma unroll
        for (int j=0;j<6;j++) W26[j*256+t] = acc[j];
        __syncthreads();
        if (t==0){ __threadfence(); atomicExch(w26flag, 1); }
        return;
    }
    if (bid < 1029){              // cast w3 -> bf16
        int i = (bid-5)*256 + t;
        whi3[i] = f2bfbits(w3[i]);
        return;
    }
    if (bid < 1541){              // cast w4 -> bf16
        int i = (bid-1029)*256 + t;
        whi4[i] = f2bfbits(w4[i]);
        return;
    }
    // ---------------- convknn worker ----------------
    const int wid = bid - 1541;
    const int b = wid & 3;
    const int si = wid >> 2;
    const int sidx = b*NS_ + si;
    const float* pb = p + (size_t)b*N_*3;
    if (t == 0){
        int v;
        while ((v = atomicAdd(&prog[sidx], 0)) == 0) { __builtin_amdgcn_s_sleep(8); }
        ciS = v - 1;
    }
    __syncthreads();
    const int ci = ciS;
    float cx = pb[ci*3+0];
    float cy = pb[ci*3+1];
    float cz = pb[ci*3+2];
    float c2 = __fadd_rn(__fadd_rn(__fmul_rn(cx,cx),__fmul_rn(cy,cy)),__fmul_rn(cz,cz));
    float d2[16];
    #pragma unroll
    for (int j=0;j<16;j++){
        int i = t*16+j;
        float x = pb[i*3+0];
        float y = pb[i*3+1];
        float z = pb[i*3+2];
        float p2 = __fadd_rn(__fadd_rn(__fmul_rn(x,x),__fmul_rn(y,y)),__fmul_rn(z,z));
        float dot= __fadd_rn(__fadd_rn(__fmul_rn(cx,x),__fmul_rn(cy,y)),__fmul_rn(cz,z));
        d2[j] = __fsub_rn(__fadd_rn(c2,p2), __fmul_rn(2.0f,dot));
    }
    for (int it=0; it<KNN_; it++){
        float lmin = min16(d2);
        float wmin = wave_min_f32(lmin);
        unsigned msk = 0;
        #pragma unroll
        for (int j=0;j<16;j++) msk |= (d2[j]==wmin) ? (1u<<j) : 0u;
        ull ball = __ballot(msk != 0);
        int srclane = (int)__builtin_ctzll(ball);
        unsigned lmsk = (unsigned)__builtin_amdgcn_readlane((int)msk, srclane);
        int widx = (wave*64 + srclane)*16 + (int)__builtin_ctz(lmsk);
        if (lane==0)
            warr[it&1][wave] = ((ull)fmono(wmin)<<32) | (unsigned)widx;
        __syncthreads();
        ull g0 = warr[it&1][0], g1 = warr[it&1][1], g2 = warr[it&1][2], g3 = warr[it&1][3];
        ull ga = g0 < g1 ? g0 : g1;
        ull gb = g2 < g3 ? g2 : g3;
        ull g  = ga < gb ? ga : gb;
        int idx = (int)(g & 0xFFFFFFFFull);
        if ((idx>>4)==t) d2[idx & 15] = INFINITY;
        if (t==0) knnS[it] = idx;
    }
    if (t == 0){ while (atomicAdd(w26flag, 0) == 0) { __builtin_amdgcn_s_sleep(8); } __threadfence(); }
    __syncthreads();
    #pragma unroll
    for (int r=0;r<6;r++) Ws[r][t] = W26[r*256+t];
    if (t < 32){
        int i = knnS[t];
        const float* fb = f + (size_t)b*3*N_;
        xs[0][t] = pb[i*3+0];
        xs[1][t] = pb[i*3+1];
        xs[2][t] = pb[i*3+2];
        xs[3][t] = fb[0*N_+i];
        xs[4][t] = fb[1*N_+i];
        xs[5][t] = fb[2*N_+i];
    }
    __syncthreads();
    float w0=Ws[0][t], w1v=Ws[1][t], w2v=Ws[2][t], w3v=Ws[3][t], w4v=Ws[4][t], w5v=Ws[5][t];
    float bias = b2[t];
    bf16* zrow = z2 + (size_t)t*NPOS_ + (size_t)sidx*KNN_;
    float ssum = 0.f, sq = 0.f;
    float mxv = -3.4e38f, mnv = 3.4e38f;   // per-(c,sidx) extrema of bf16(z2)
    for (int k0=0;k0<32;k0+=8){
        float y[8];
        #pragma unroll
        for (int u=0;u<8;u++){
            int k = k0+u;
            float acc = bias;
            acc = fmaf(w0, xs[0][k], acc);
            acc = fmaf(w1v,xs[1][k], acc);
            acc = fmaf(w2v,xs[2][k], acc);
            acc = fmaf(w3v,xs[3][k], acc);
            acc = fmaf(w4v,xs[4][k], acc);
            acc = fmaf(w5v,xs[5][k], acc);
            float vr = bits2f(f2bfbits(acc));
            ssum += vr; sq = fmaf(vr, vr, sq);
            mxv = fmaxf(mxv, vr); mnv = fminf(mnv, vr);
            y[u] = acc;
        }
        *reinterpret_cast<uint4*>(zrow + k0) = pack8(y);
    }
    // packed extrema, [sidx][c] layout: each worker writes its own 1KB run
    mxmn2[(size_t)sidx*256 + t] = (unsigned)f2bfbits(mxv) | ((unsigned)f2bfbits(mnv)<<16);
    const int slot = wid & (NSLOT-1);
    atomicAdd(&part[(size_t)(t*2+0)*NSLOT + slot], ssum);
    atomicAdd(&part[(size_t)(t*2+1)*NSLOT + slot], sq);
}

// -------- xm = max over K of relu(a*x+b) via packed per-(bs,c) extrema --------
// max_k relu(a*x_k+b) = relu(a*mx+b) if a>=0 else relu(a*mn+b)  (monotone fmaf)
// Block = 32 bs x 256 c; thread t owns channel c=t, writes 64B (full line) runs.
__global__ __launch_bounds__(256) void xm_kernel(const unsigned* __restrict__ mxmn2,
                                                 const float2* __restrict__ ab,
                                                 bf16* __restrict__ xm){
    const int t = threadIdx.x;
    const int bs0 = blockIdx.x * 32;
    float2 s = ab[t];
    us y[32];
    #pragma unroll
    for (int i=0;i<32;i++){
        unsigned v = mxmn2[(size_t)(bs0+i)*256 + t];
        float x = (s.x >= 0.f) ? bits2f((us)(v & 0xFFFFu)) : bits2f((us)(v >> 16));
        y[i] = f2bfbits(fmaxf(fmaf(x, s.x, s.y), 0.0f));
    }
    uint4* dst = reinterpret_cast<uint4*>(reinterpret_cast<us*>(xm) + (size_t)t*4096 + bs0);
    const uint4* src = reinterpret_cast<const uint4*>(y);
    dst[0]=src[0]; dst[1]=src[1]; dst[2]=src[2]; dst[3]=src[3];
}

// -------------------- small fp32 GEMM (t3 only) --------------------
__global__ __launch_bounds__(256) void gemm128(const float* __restrict__ A, int lda, int aoff,
                                               const bf16* __restrict__ B,
                                               int M, int N, int K,
                                               float* __restrict__ Cf){
    __shared__ float As[16][128];
    __shared__ float Bs[16][128];
    const int tid = threadIdx.x;
    const int tx = tid & 15, ty = tid >> 4;
    const int m0 = blockIdx.y*128, n0 = blockIdx.x*128;
    float acc[8][8];
    #pragma unroll
    for (int i=0;i<8;i++)
        #pragma unroll
        for (int j=0;j<8;j++) acc[i][j]=0.f;
    const int arow = tid >> 1, akg = tid & 1;
    const int bkk = tid >> 4, bng = tid & 15;
    for (int k0=0;k0<K;k0+=16){
        const float* aptr = A + (size_t)(m0+arow)*lda + aoff + k0 + akg*8;
        float4 a0 = *reinterpret_cast<const float4*>(aptr);
        float4 a1 = *reinterpret_cast<const float4*>(aptr+4);
        As[akg*8+0][arow]=a0.x; As[akg*8+1][arow]=a0.y;
        As[akg*8+2][arow]=a0.z; As[akg*8+3][arow]=a0.w;
        As[akg*8+4][arow]=a1.x; As[akg*8+5][arow]=a1.y;
        As[akg*8+6][arow]=a1.z; As[akg*8+7][arow]=a1.w;
        uint4 bv = *reinterpret_cast<const uint4*>(B + (size_t)(k0+bkk)*N + n0 + bng*8);
        float bf[8]; unpack8(bv, bf);
        *reinterpret_cast<float4*>(&Bs[bkk][bng*8+0]) = make_float4(bf[0],bf[1],bf[2],bf[3]);
        *reinterpret_cast<float4*>(&Bs[bkk][bng*8+4]) = make_float4(bf[4],bf[5],bf[6],bf[7]);
        __syncthreads();
        #pragma unroll
        for (int kk=0;kk<16;kk++){
            float a[8], b[8];
            *reinterpret_cast<float4*>(&a[0]) = *reinterpret_cast<float4*>(&As[kk][ty*8+0]);
            *reinterpret_cast<float4*>(&a[4]) = *reinterpret_cast<float4*>(&As[kk][ty*8+4]);
            *reinterpret_cast<float4*>(&b[0]) = *reinterpret_cast<float4*>(&Bs[kk][tx*8+0]);
            *reinterpret_cast<float4*>(&b[4]) = *reinterpret_cast<float4*>(&Bs[kk][tx*8+4]);
            #pragma unroll
            for (int i=0;i<8;i++)
                #pragma unroll
                for (int j=0;j<8;j++)
                    acc[i][j] = fmaf(a[i], b[j], acc[i][j]);
        }
        __syncthreads();
    }
    const int n = n0 + tx*8;
    #pragma unroll
    for (int i=0;i<8;i++){
        int m = m0 + ty*8 + i;
        *reinterpret_cast<float4*>(Cf + (size_t)m*N + n + 0) = make_float4(acc[i][0],acc[i][1],acc[i][2],acc[i][3]);
        *reinterpret_cast<float4*>(Cf + (size_t)m*N + n + 4) = make_float4(acc[i][4],acc[i][5],acc[i][6],acc[i][7]);
    }
}

// -------------------- MFMA GEMM: LDS-staged bf16 A, fused-BN B, fused stats ---
// When mxmnout!=nullptr: do NOT write the dense output; instead emit packed
// per-(row,sidx) max/min over the 32 k-columns (pool fusion for final maxpool).
//
// T1 XCD swizzle: same-n M-tile groups made consecutive-on-one-XCD.
#define LDK 40
__global__ __launch_bounds__(256) void gemm_mfma(const us* __restrict__ Whi,
                                                 int ldw, int aoff,
                                                 const bf16* __restrict__ act, int K,
                                                 const float2* __restrict__ ab,
                                                 bf16* __restrict__ out,
                                                 const float* __restrict__ t3,
                                                 float* __restrict__ part, int chbase,
                                                 unsigned* __restrict__ mxmnout){
    __shared__ __align__(16) us AsH[128*LDK];
    __shared__ __align__(16) us Bs [128*LDK];
    __shared__ float t3s[128][4];
    const us* actu = reinterpret_cast<const us*>(act);
    const int t = threadIdx.x;
    // ---- XCD-aware tile assignment (bijective remap of the linear id) ----
    const int nx  = gridDim.x;
    const int nwg = nx * gridDim.y;
    const int hid = blockIdx.y * nx + blockIdx.x;
    const int q8  = nwg >> 3;
    const int logical = (hid & 7) * q8 + (hid >> 3);
    const int mi = logical % nx;
    const int ni = logical / nx;
    const int m0 = mi*128, n0 = ni*128;
    const int wave = t>>6, lane = t&63;
    const int wm = wave>>1, wn = wave&1;
    const int q = lane>>4, col = lane&15;

    if (t3 && t < 128){
        const float* src = t3 + (size_t)(m0+t)*4096 + (n0>>5);
        t3s[t][0]=src[0]; t3s[t][1]=src[1]; t3s[t][2]=src[2]; t3s[t][3]=src[3];
    }

    f32x4 acc[4][4];
    #pragma unroll
    for (int i=0;i<4;i++)
        #pragma unroll
        for (int j=0;j<4;j++) acc[i][j] = (f32x4){0.f,0.f,0.f,0.f};

    const int ar = t>>1, ah = t&1;
    const int bn = t&127, bh = t>>7;

    for (int k0=0;k0<K;k0+=32){
        const us* sh = Whi + (size_t)(m0+ar)*ldw + aoff + k0 + ah*16;
        uint4 h0 = *reinterpret_cast<const uint4*>(sh);
        uint4 h1 = *reinterpret_cast<const uint4*>(sh+8);
        *reinterpret_cast<uint4*>(&AsH[ar*LDK + ah*16 + 0]) = h0;
        *reinterpret_cast<uint4*>(&AsH[ar*LDK + ah*16 + 8]) = h1;
        us bvals[16];
        #pragma unroll
        for (int j=0;j<16;j++){
            int k = k0 + bh*16 + j;
            float x = bits2f(actu[(size_t)k*NPOS_ + n0 + bn]);
            float2 s = ab[k];
            bvals[j] = f2bfbits(fmaxf(fmaf(x, s.x, s.y), 0.0f));
        }
        *reinterpret_cast<uint4*>(&Bs[bn*LDK + bh*16 + 0]) = *reinterpret_cast<uint4*>(&bvals[0]);
        *reinterpret_cast<uint4*>(&Bs[bn*LDK + bh*16 + 8]) = *reinterpret_cast<uint4*>(&bvals[8]);
        __syncthreads();
        short8 bf[4], afh[4];
        #pragma unroll
        for (int tn=0;tn<4;tn++)
            bf[tn] = *reinterpret_cast<const short8*>(&Bs[(wn*64+tn*16+col)*LDK + q*8]);
        #pragma unroll
        for (int tm=0;tm<4;tm++)
            afh[tm] = *reinterpret_cast<const short8*>(&AsH[(wm*64+tm*16+col)*LDK + q*8]);
        #pragma unroll
        for (int tm=0;tm<4;tm++)
            #pragma unroll
            for (int tn=0;tn<4;tn++)
                acc[tm][tn] = __builtin_amdgcn_mfma_f32_16x16x32_bf16(afh[tm], bf[tn], acc[tm][tn], 0, 0, 0);
        __syncthreads();
    }
    const int slot = ni & (NSLOT-1);
    #pragma unroll
    for (int tm=0;tm<4;tm++){
        #pragma unroll
        for (int r=0;r<4;r++){
            int m_l = wm*64 + tm*16 + q*4 + r;
            float srow = 0.f, qrow = 0.f;
            float vr4[4];
            #pragma unroll
            for (int tn=0;tn<4;tn++){
                int n_l = wn*64 + tn*16 + col;
                float vv = acc[tm][tn][r];
                if (t3) vv += t3s[m_l][n_l>>5];
                us hb = f2bfbits(vv);
                if (!mxmnout)
                    reinterpret_cast<us*>(out)[(size_t)(m0+m_l)*NPOS_ + n0 + n_l] = hb;
                float vr = bits2f(hb);
                vr4[tn] = vr;
                srow += vr; qrow = fmaf(vr, vr, qrow);
            }
            srow = rowsum16(srow);
            qrow = rowsum16(qrow);
            if (col == 15){
                atomicAdd(&part[(size_t)((chbase + m0 + m_l)*2+0)*NSLOT + slot], srow);
                atomicAdd(&part[(size_t)((chbase + m0 + m_l)*2+1)*NSLOT + slot], qrow);
            }
            if (mxmnout){
                unsigned pk[2];
                #pragma unroll
                for (int h=0;h<2;h++){
                    float mxl = fmaxf(vr4[2*h], vr4[2*h+1]);
                    float mnl = fminf(vr4[2*h], vr4[2*h+1]);
                    mxl = rowmax16(mxl);
                    mnl = rowmin16(mnl);
                    pk[h] = (unsigned)f2bfbits(mxl) | ((unsigned)f2bfbits(mnl)<<16);
                }
                if (col == 15){
                    int bsi = (n0>>5) + wn*2;
                    *reinterpret_cast<uint2*>(&mxmnout[(size_t)(m0+m_l)*4096 + bsi]) =
                        make_uint2(pk[0], pk[1]);
                }
            }
        }
    }
}

// ---- final: fused bn4-coef + BN4 + ReLU + maxpool via packed extrema ---------
__global__ __launch_bounds__(256) void final_kernel(const unsigned* __restrict__ mxmn4,
                                                    const float* __restrict__ part,
                                                    const float* __restrict__ g4,
                                                    const float* __restrict__ be4,
                                                    float* __restrict__ out){
    __shared__ float abS[2];
    const int t = threadIdx.x;
    const int c = (blockIdx.x >> 2) & 255;
    const int b = blockIdx.x >> 10;
    const int s = ((blockIdx.x & 3) << 8) | t;
    if (t < 64){
        float ss = part[(size_t)((768+c)*2+0)*NSLOT + t];
        float qq = part[(size_t)((768+c)*2+1)*NSLOT + t];
        ss = wave_sum_f32(ss);
        qq = wave_sum_f32(qq);
        if (t==0){
            const float inv = 1.0f/(float)NPOS_;
            float mean = ss*inv;
            float var  = qq*inv - mean*mean;
            float a = g4[c]*rsqrtf(var + BN_EPS_);
            abS[0] = a; abS[1] = be4[c] - mean*a;
        }
    }
    __syncthreads();
    const float a = abS[0], bb = abS[1];
    const int bsi = b*NS_ + s;
    unsigned v = mxmn4[(size_t)c*4096 + bsi];
    float x = (a >= 0.f) ? bits2f((us)(v & 0xFFFFu)) : bits2f((us)(v >> 16));
    out[(size_t)(b*256 + c)*NS_ + s] = fmaxf(fmaf(x, a, bb), 0.0f);
}

extern "C" void kernel_launch(void* const* d_in, const int* in_sizes, int n_in,
                              void* d_out, int out_size, void* d_ws, size_t ws_size,
                              hipStream_t stream) {
    const float* p   = (const float*)d_in[0];
    const float* f   = (const float*)d_in[1];
    const float* w1  = (const float*)d_in[2];
    const float* w2  = (const float*)d_in[3];
    const float* b2  = (const float*)d_in[4];
    const float* g2  = (const float*)d_in[5];
    const float* be2 = (const float*)d_in[6];
    const float* w3  = (const float*)d_in[7];
    const float* g3  = (const float*)d_in[8];
    const float* be3 = (const float*)d_in[9];
    const float* w4  = (const float*)d_in[10];
    const float* g4  = (const float*)d_in[11];
    const float* be4 = (const float*)d_in[12];

    // Workspace (~215 MB); aliases:
    //   mxmn2 (4 MB) aliases t3 -- read by xm (disp 3) BEFORE gemm128 writes t3 (disp 4)
    //   mxmn4 (4 MB) aliases z2 -- written by gemm7 (disp 7) AFTER z2's last read (disp 5)
    char* ws = (char*)d_ws;
    float*    W26   = (float*)(ws + 540672);        // 6 KB
    float2*   ab2   = (float2*)(ws + 555008);       // 2 KB
    float2*   ab3   = (float2*)(ws + 557056);       // 4 KB
    us*       whi3  = (us*)(ws + 561152);           // 512 KB
    us*       whi4  = (us*)(ws + 1609728);          // 256 KB
    float*    t3    = (float*)(ws + 2134016);       // 8 MB
    unsigned* mxmn2 = (unsigned*)(ws + 2134016);    // 4 MB (aliases t3)
    bf16*     z2    = (bf16*)(ws + 10522624);       // 64 MB
    unsigned* mxmn4 = (unsigned*)(ws + 10522624);   // 4 MB (aliases z2, post disp-5)
    bf16*     xm    = (bf16*)(ws + 77631488);       // 2 MB
    bf16*     z3    = (bf16*)(ws + 79728640);       // 128 MB (end 213946368)
    float*    part  = (float*)(ws + 213946368);     // 512 KB partial stats
    int*      prog  = (int*)(ws + 214470656);       // 16 KB progress words
    int*      w26flag = (int*)(ws + 214487040);     // 4 B

    float* out_cntrd = (float*)d_out;
    float* out_feat  = (float*)d_out + (size_t)B_*NS_*3;

    // 0: zero part + prog + w26flag in one capturable memset
    hipMemsetAsync(ws + 213946368, 0, 540676, stream);
    // 1: FPS producer + preps + convknn consumers
    mega_kernel<<<5637, 256, 0, stream>>>(p, f, out_cntrd, part, prog, w26flag,
                                          w1, w2, W26, b2,
                                          w3, whi3, w4, whi4, z2, mxmn2);
    // 2: BN2 coefficients
    bn_coef<<<1, 256, 0, stream>>>(part, g2, be2, 0, 256, ab2);
    // 3: xm = max_k relu(bn2(z2)) from packed extrema
    xm_kernel<<<128, 256, 0, stream>>>(mxmn2, ab2, xm);
    // 4: t3 = w3[:, :256] @ xm
    gemm128<<<dim3(32,4), 256, 0, stream>>>(w3, 512, 0, xm, 512, 4096, 256, t3);
    // 5: z3 = w3[:, 256:] @ relu(bn2(z2)) + t3   (+ BN3 partial stats)
    gemm_mfma<<<dim3(4,1024), 256, 0, stream>>>(whi3, 512, 256, z2, 256, ab2, z3, t3, part, 256,
                                                nullptr);
    // 6: BN3 coefficients
    bn_coef<<<2, 256, 0, stream>>>(part, g3, be3, 256, 512, ab3);
    // 7: w4 @ relu(bn3(z3)) -> packed per-(c,bsi) max/min (+ BN4 partial stats)
    gemm_mfma<<<dim3(2,1024), 256, 0, stream>>>(whi4, 512, 0, z3, 512, ab3, nullptr, nullptr, part, 768,
                                                mxmn4);
    // 8: fused bn4-coef + BN4 + ReLU + maxpool -> out
    final_kernel<<<4096, 256, 0, stream>>>(mxmn4, part, g4, be4, out_feat);
}